// Round 1
// 394.281 us; speedup vs baseline: 1.0116x; 1.0116x over previous
//
#include <hip/hip_runtime.h>

typedef __bf16 bf16_t;
typedef _Float16 f16_t;
typedef f16_t f16x4 __attribute__((ext_vector_type(4)));
typedef bf16_t bf16x2 __attribute__((ext_vector_type(2)));
typedef bf16_t bf16x4 __attribute__((ext_vector_type(4)));
typedef bf16_t bf16x8 __attribute__((ext_vector_type(8)));
typedef float f32x4 __attribute__((ext_vector_type(4)));
typedef float f32x16 __attribute__((ext_vector_type(16)));

#define MFMA16(a, b, c) __builtin_amdgcn_mfma_f32_16x16x32_bf16(a, b, c, 0, 0, 0)
#define MFMA32(a, b, c) __builtin_amdgcn_mfma_f32_32x32x16_bf16(a, b, c, 0, 0, 0)

__device__ __forceinline__ float leaky01(float v) { return v >= 0.f ? v : 0.01f * v; }

// packed-weight offsets (bf16 elements): hi at OFF, lo at OFF+size
#define OFF_IW1 0         // 256x128
#define OFF_IW2 65536     // 128x128
#define OFF_IW3 98304     // 128x256
#define OFF_AW1 163840    // 256x128
#define OFF_AW2 229376    // 128x128
#define OFF_AW3 262144    // 128x256
#define OFF_PW1 327680    // 256x256
#define OFF_PW2 458752    // 256x256
#define OFF_M3  589824    // 128x128
#define WP_TOTAL 622592

// ---------------------------------------------------------------------------
// 16x16x32 GEMM tile: 32 rows x (NCT*16 cols per wave), K=KD, NC = out cols.
// Used for narrow (128-col) layers where 8 waves x 16 cols covers NC.
// ---------------------------------------------------------------------------
template<int KD, int NC, int NCT>
__device__ __forceinline__ void gemm_tile(
    const bf16_t* __restrict__ ah, const bf16_t* __restrict__ al, int sa,
    const bf16_t* __restrict__ Bh, const bf16_t* __restrict__ Bl,
    int cb, int qd, int ln, f32x4 (&acc)[2][4])
{
#pragma unroll
    for (int rt = 0; rt < 2; ++rt)
#pragma unroll
        for (int ct = 0; ct < NCT; ++ct) acc[rt][ct] = (f32x4){0.f, 0.f, 0.f, 0.f};
#pragma unroll
    for (int k0 = 0; k0 < KD; k0 += 32) {
        int ka = k0 + qd * 8;
        bf16x8 a0h = *(const bf16x8*)&ah[ln * sa + ka];
        bf16x8 a1h = *(const bf16x8*)&ah[(16 + ln) * sa + ka];
        bf16x8 a0l = *(const bf16x8*)&al[ln * sa + ka];
        bf16x8 a1l = *(const bf16x8*)&al[(16 + ln) * sa + ka];
#pragma unroll
        for (int ct = 0; ct < NCT; ++ct) {
            size_t bo = ((size_t)((k0 >> 5) * 4 + qd) * NC + cb + ct * 16 + ln) * 8;
            bf16x8 bh = *(const bf16x8*)(Bh + bo);
            bf16x8 bl = *(const bf16x8*)(Bl + bo);
            acc[0][ct] = MFMA16(a0h, bh, acc[0][ct]);
            acc[0][ct] = MFMA16(a0l, bh, acc[0][ct]);
            acc[0][ct] = MFMA16(a0h, bl, acc[0][ct]);
            acc[1][ct] = MFMA16(a1h, bh, acc[1][ct]);
            acc[1][ct] = MFMA16(a1l, bh, acc[1][ct]);
            acc[1][ct] = MFMA16(a1h, bl, acc[1][ct]);
        }
    }
}

// ---------------------------------------------------------------------------
// 32x32x16 GEMM tile: one 32x32 output tile per wave.
// 48 FLOP per LDS byte (vs 24 for the 16x16 path) -> LDS off critical path.
// Fragment order of the packed weights is identical to the 16x16 layout:
// group (k>>3) x col x 8 contiguous k. Two interleaved acc chains keep MFMA
// dependency distance >= 2.
// l31 = lane&31 (row for A, col for B), kh = lane>>5 (k-half).
// ---------------------------------------------------------------------------
template<int KD, int NC>
__device__ __forceinline__ void gemm32_tile(
    const bf16_t* __restrict__ ah, const bf16_t* __restrict__ al, int sa,
    const bf16_t* __restrict__ Bh, const bf16_t* __restrict__ Bl,
    int cb, int l31, int kh, f32x16 &acc)
{
    f32x16 c0, c1;
#pragma unroll
    for (int i = 0; i < 16; ++i) { c0[i] = 0.f; c1[i] = 0.f; }
    const int arow = l31 * sa + kh * 8;
    const int bcol = cb + l31;
#pragma unroll
    for (int kc = 0; kc < KD; kc += 32) {
        bf16x8 ah0 = *(const bf16x8*)&ah[arow + kc];
        bf16x8 al0 = *(const bf16x8*)&al[arow + kc];
        bf16x8 ah1 = *(const bf16x8*)&ah[arow + kc + 16];
        bf16x8 al1 = *(const bf16x8*)&al[arow + kc + 16];
        size_t bo0 = ((size_t)((kc >> 3) + kh) * NC + bcol) * 8;
        size_t bo1 = ((size_t)((kc >> 3) + 2 + kh) * NC + bcol) * 8;
        bf16x8 bh0 = *(const bf16x8*)(Bh + bo0);
        bf16x8 bl0 = *(const bf16x8*)(Bl + bo0);
        bf16x8 bh1 = *(const bf16x8*)(Bh + bo1);
        bf16x8 bl1 = *(const bf16x8*)(Bl + bo1);
        c0 = MFMA32(ah0, bh0, c0);
        c1 = MFMA32(ah1, bh1, c1);
        c0 = MFMA32(al0, bh0, c0);
        c1 = MFMA32(al1, bh1, c1);
        c0 = MFMA32(ah0, bl0, c0);
        c1 = MFMA32(ah1, bl1, c1);
    }
    acc = c0 + c1;
}

// 16x16 epilogue -> split-bf16 LDS, act: 0 none, 1 leaky, 2 relu
template<int NCT>
__device__ __forceinline__ void epi_split(
    f32x4 (&acc)[2][4], const float* __restrict__ bias,
    int cb, int qd, int ln, bf16_t* dh, bf16_t* dl, int stride, int act)
{
#pragma unroll
    for (int ct = 0; ct < NCT; ++ct) {
        int col = cb + ct * 16 + ln;
        float bb = bias ? bias[col] : 0.f;
#pragma unroll
        for (int rt = 0; rt < 2; ++rt)
#pragma unroll
            for (int r = 0; r < 4; ++r) {
                float v = acc[rt][ct][r] + bb;
                if (act == 1) v = leaky01(v);
                else if (act == 2) v = fmaxf(v, 0.f);
                int row = rt * 16 + qd * 4 + r;
                bf16_t h = (bf16_t)v;
                dh[row * stride + col] = h;
                dl[row * stride + col] = (bf16_t)(v - (float)h);
            }
    }
}

// 32x32 epilogue -> split-bf16 LDS. C/D layout: col=lane&31,
// row=(reg&3)+8*(reg>>2)+4*(lane>>5).
template<int ACT>
__device__ __forceinline__ void epi32_split(
    const f32x16 &acc, const float* __restrict__ bias,
    int cb, int l31, int kh, bf16_t* dh, bf16_t* dl, int stride)
{
    int col = cb + l31;
    float bb = bias[col];
#pragma unroll
    for (int r = 0; r < 16; ++r) {
        float v = acc[r] + bb;
        if (ACT == 1) v = leaky01(v);
        else if (ACT == 2) v = fmaxf(v, 0.f);
        int row = (r & 3) + 8 * (r >> 2) + 4 * kh;
        bf16_t h = (bf16_t)v;
        dh[row * stride + col] = h;
        dl[row * stride + col] = (bf16_t)(v - (float)h);
    }
}

// ---------------------------------------------------------------------------
// kernelA: 512 thr / 32 rows. 32x32 split-dual: waves 0-3 z = h@aW1,
// waves 4-7 y1 = leaky(h@iW1+ib1). Then y2 = leaky(y1@iW2+ib2);
// zinv = y2@M3 + c3.  z,zinv (fp16) interleaved in zbuf.
// Extra blocks (blockIdx >= tiles) do the CSR edge count.
// ---------------------------------------------------------------------------
__global__ __launch_bounds__(512, 4) void kernelA(
    const float* __restrict__ h, f16_t* __restrict__ zbuf,
    const bf16_t* __restrict__ wp, const float* __restrict__ ib1,
    const float* __restrict__ ib2, const float* __restrict__ c3f, int M,
    int tiles, const int* __restrict__ dstE, int* __restrict__ cnt, int E)
{
    __shared__ bf16_t Xh[32][264], Xl[32][264];
    __shared__ bf16_t Yh[32][136], Yl[32][136];

    const int tid = threadIdx.x;

    if ((int)blockIdx.x >= tiles) {   // edge-count blocks
        int e = (blockIdx.x - tiles) * 512 + tid;
        if (e < E) atomicAdd(&cnt[dstE[e]], 1);
        return;
    }

    const int row0 = blockIdx.x * 32;
    const int lane = tid & 63;
    const int wv = tid >> 6;          // 0..7
    const int qd = lane >> 4;
    const int ln = lane & 15;
    const int cb = wv * 16;
    const int l31 = lane & 31;
    const int kh = lane >> 5;

    // stage h (32 x 256 fp32) -> split bf16
    {
        const float4* src4 = (const float4*)(h + (size_t)row0 * 256);
#pragma unroll
        for (int i = 0; i < 4; ++i) {
            int q = i * 512 + tid;
            int row = q >> 6;
            int kc = (q & 63) * 4;
            float4 v = make_float4(0.f, 0.f, 0.f, 0.f);
            if (row0 + row < M) v = src4[q];
            bf16_t h0 = (bf16_t)v.x; bf16_t l0 = (bf16_t)(v.x - (float)h0);
            bf16_t h1 = (bf16_t)v.y; bf16_t l1 = (bf16_t)(v.y - (float)h1);
            bf16_t h2 = (bf16_t)v.z; bf16_t l2 = (bf16_t)(v.z - (float)h2);
            bf16_t h3 = (bf16_t)v.w; bf16_t l3 = (bf16_t)(v.w - (float)h3);
            *(bf16x4*)&Xh[row][kc] = (bf16x4){h0, h1, h2, h3};
            *(bf16x4*)&Xl[row][kc] = (bf16x4){l0, l1, l2, l3};
        }
    }
    __syncthreads();

    // split-dual 32x32: waves 0-3 -> z (aW1), waves 4-7 -> y1 (iW1)
    {
        const bool isz = wv < 4;
        const int cb32 = (wv & 3) * 32;
        const bf16_t* Bh = wp + (isz ? OFF_AW1 : OFF_IW1);
        f32x16 a32;
        gemm32_tile<256, 128>(&Xh[0][0], &Xl[0][0], 264, Bh, Bh + 32768,
                              cb32, l31, kh, a32);
        int col = cb32 + l31;
        if (isz) {
#pragma unroll
            for (int r = 0; r < 16; ++r) {
                int lrow = (r & 3) + 8 * (r >> 2) + 4 * kh;
                int row = row0 + lrow;
                if (row < M) zbuf[((size_t)row * 2) * 128 + col] = (f16_t)a32[r];
            }
        } else {
            float bb = ib1[col];
#pragma unroll
            for (int r = 0; r < 16; ++r) {
                int lrow = (r & 3) + 8 * (r >> 2) + 4 * kh;
                float v = leaky01(a32[r] + bb);
                bf16_t hh = (bf16_t)v;
                Yh[lrow][col] = hh;
                Yl[lrow][col] = (bf16_t)(v - (float)hh);
            }
        }
    }
    __syncthreads();

    f32x4 acc[2][4];

    // y2 = leaky(y1@iW2 + ib2) -> X (h dead)
    gemm_tile<128, 128, 1>(&Yh[0][0], &Yl[0][0], 136, wp + OFF_IW2, wp + OFF_IW2 + 16384, cb, qd, ln, acc);
    epi_split<1>(acc, ib2, cb, qd, ln, &Xh[0][0], &Xl[0][0], 264, 1);
    __syncthreads();

    // zinv = y2 @ M3 + c3 -> zbuf odd rows (fp16)
    gemm_tile<128, 128, 1>(&Xh[0][0], &Xl[0][0], 264, wp + OFF_M3, wp + OFF_M3 + 16384, cb, qd, ln, acc);
    {
        int col = cb + ln;
        float bb = c3f[col];
#pragma unroll
        for (int rt = 0; rt < 2; ++rt)
#pragma unroll
            for (int r = 0; r < 4; ++r) {
                int row = row0 + rt * 16 + qd * 4 + r;
                if (row < M) zbuf[((size_t)row * 2 + 1) * 128 + col] = (f16_t)(acc[rt][0][r] + bb);
            }
    }
}

// ---------------------------------------------------------------------------
// kernelB: 512 thr / 32 rows. Phase 0 = mean gather, half-wave per node.
// Narrow (128-col) layers: 16x16 path. Wide (256-col) layers: 32x32 path.
// ---------------------------------------------------------------------------
__global__ __launch_bounds__(512, 4) void kernelB(
    const f16_t* __restrict__ zbuf, const int* __restrict__ ridx,
    const int* __restrict__ offs, const int* __restrict__ cnt,
    const float* __restrict__ ab1, const int* __restrict__ invf,
    float* __restrict__ out, const bf16_t* __restrict__ wp,
    const float* __restrict__ ab2, const float* __restrict__ ab3,
    const float* __restrict__ ib1, const float* __restrict__ ib2,
    const float* __restrict__ ib3, const float* __restrict__ pb1,
    const float* __restrict__ pb2, int M)
{
    __shared__ bf16_t Ch[32][264], Cl[32][264];
    __shared__ bf16_t Ah[32][136], Al[32][136];
    __shared__ int sflag[32];

    const int tid = threadIdx.x;
    const int row0 = blockIdx.x * 32;
    const int lane = tid & 63;
    const int wv = tid >> 6;
    const int qd = lane >> 4;
    const int ln = lane & 15;
    const int cb2 = wv * 16;
    const int l31 = lane & 31;
    const int kh = lane >> 5;
    const int cb32 = wv * 32;

    // ---- phase 0: mean gather, half-wave (32 lanes x f16x4 = 256B row) per node
    const int hw = tid >> 5;          // half-wave 0..15
    const int hl = tid & 31;          // lane in half
    const int hbase = lane & 32;      // shfl base within wave
    const f16x4* zp4 = (const f16x4*)zbuf;   // row = 32 f16x4

#pragma unroll
    for (int pass = 0; pass < 2; ++pass) {
        int nl = pass * 16 + hw;
        int row = row0 + nl;
        float s0 = 0.f, s1 = 0.f, s2 = 0.f, s3 = 0.f;
        int c = 0;
        if (row < M) {
            int beg = offs[row];
            c = cnt[row];
            for (int base = 0; base < c; base += 32) {
                int rem = c - base; if (rem > 32) rem = 32;
                int myr = (hl < rem) ? ridx[beg + base + hl] : 0;
                int j = 0;
                for (; j + 8 <= rem; j += 8) {
                    int r0 = __shfl(myr, hbase + j + 0);
                    int r1 = __shfl(myr, hbase + j + 1);
                    int r2 = __shfl(myr, hbase + j + 2);
                    int r3 = __shfl(myr, hbase + j + 3);
                    int r4 = __shfl(myr, hbase + j + 4);
                    int r5 = __shfl(myr, hbase + j + 5);
                    int r6 = __shfl(myr, hbase + j + 6);
                    int r7 = __shfl(myr, hbase + j + 7);
                    f16x4 v0 = zp4[(size_t)r0 * 32 + hl];
                    f16x4 v1 = zp4[(size_t)r1 * 32 + hl];
                    f16x4 v2 = zp4[(size_t)r2 * 32 + hl];
                    f16x4 v3 = zp4[(size_t)r3 * 32 + hl];
                    f16x4 v4 = zp4[(size_t)r4 * 32 + hl];
                    f16x4 v5 = zp4[(size_t)r5 * 32 + hl];
                    f16x4 v6 = zp4[(size_t)r6 * 32 + hl];
                    f16x4 v7 = zp4[(size_t)r7 * 32 + hl];
                    s0 += (float)v0.x + (float)v1.x + (float)v2.x + (float)v3.x
                        + (float)v4.x + (float)v5.x + (float)v6.x + (float)v7.x;
                    s1 += (float)v0.y + (float)v1.y + (float)v2.y + (float)v3.y
                        + (float)v4.y + (float)v5.y + (float)v6.y + (float)v7.y;
                    s2 += (float)v0.z + (float)v1.z + (float)v2.z + (float)v3.z
                        + (float)v4.z + (float)v5.z + (float)v6.z + (float)v7.z;
                    s3 += (float)v0.w + (float)v1.w + (float)v2.w + (float)v3.w
                        + (float)v4.w + (float)v5.w + (float)v6.w + (float)v7.w;
                }
                for (; j < rem; ++j) {
                    int rr = __shfl(myr, hbase + j);
                    f16x4 v = zp4[(size_t)rr * 32 + hl];
                    s0 += (float)v.x; s1 += (float)v.y;
                    s2 += (float)v.z; s3 += (float)v.w;
                }
            }
        }
        float invc = 1.0f / fmaxf((float)c, 1.0f);
        float4 bv = *(const float4*)&ab1[hl * 4];
        float m0 = leaky01(s0 * invc + bv.x);
        float m1 = leaky01(s1 * invc + bv.y);
        float m2 = leaky01(s2 * invc + bv.z);
        float m3 = leaky01(s3 * invc + bv.w);
        bf16_t h0 = (bf16_t)m0; bf16_t l0 = (bf16_t)(m0 - (float)h0);
        bf16_t h1 = (bf16_t)m1; bf16_t l1 = (bf16_t)(m1 - (float)h1);
        bf16_t h2 = (bf16_t)m2; bf16_t l2 = (bf16_t)(m2 - (float)h2);
        bf16_t h3 = (bf16_t)m3; bf16_t l3 = (bf16_t)(m3 - (float)h3);
        *(bf16x4*)&Ah[nl][hl * 4] = (bf16x4){h0, h1, h2, h3};
        *(bf16x4*)&Al[nl][hl * 4] = (bf16x4){l0, l1, l2, l3};
    }
    if (tid < 32) {
        int rr = row0 + tid;
        sflag[tid] = (rr < M) ? invf[rr] : 0;
    }
    __syncthreads();

    f32x4 acc[2][4];
    f32x16 c32;

    // L2a: u = leaky(y@aW2 + ab2) -> A (in place)
    gemm_tile<128, 128, 1>(&Ah[0][0], &Al[0][0], 136, wp + OFF_AW2, wp + OFF_AW2 + 16384, cb2, qd, ln, acc);
    __syncthreads();
    epi_split<1>(acc, ab2, cb2, qd, ln, &Ah[0][0], &Al[0][0], 136, 1);
    __syncthreads();

    // L3a: res = u@aW3 + ab3 -> C   (32x32: 8 waves x 32 cols = 256)
    gemm32_tile<128, 256>(&Ah[0][0], &Al[0][0], 136, wp + OFF_AW3, wp + OFF_AW3 + 32768, cb32, l31, kh, c32);
    epi32_split<0>(c32, ab3, cb32, l31, kh, &Ch[0][0], &Cl[0][0], 264);
    __syncthreads();

    // inv layer1: t1 = leaky(res@iW1 + ib1) -> A
    gemm_tile<256, 128, 1>(&Ch[0][0], &Cl[0][0], 264, wp + OFF_IW1, wp + OFF_IW1 + 32768, cb2, qd, ln, acc);
    epi_split<1>(acc, ib1, cb2, qd, ln, &Ah[0][0], &Al[0][0], 136, 1);
    __syncthreads();

    // inv layer2: t2 = leaky(t1@iW2 + ib2) -> A (in place)
    gemm_tile<128, 128, 1>(&Ah[0][0], &Al[0][0], 136, wp + OFF_IW2, wp + OFF_IW2 + 16384, cb2, qd, ln, acc);
    __syncthreads();
    epi_split<1>(acc, ib2, cb2, qd, ln, &Ah[0][0], &Al[0][0], 136, 1);
    __syncthreads();

    // inv layer3: overwrite C rows where flag set  (32x32)
    gemm32_tile<128, 256>(&Ah[0][0], &Al[0][0], 136, wp + OFF_IW3, wp + OFF_IW3 + 32768, cb32, l31, kh, c32);
    {
        int col = cb32 + l31;
        float bb = ib3[col];
#pragma unroll
        for (int r = 0; r < 16; ++r) {
            int row = (r & 3) + 8 * (r >> 2) + 4 * kh;
            if (sflag[row] == 1) {
                float v = c32[r] + bb;
                bf16_t hh = (bf16_t)v;
                Ch[row][col] = hh;
                Cl[row][col] = (bf16_t)(v - (float)hh);
            }
        }
    }
    __syncthreads();

    // proj1: p1 = relu(sel@pW1 + pb1) -> C (in place, 32x32)
    gemm32_tile<256, 256>(&Ch[0][0], &Cl[0][0], 264, wp + OFF_PW1, wp + OFF_PW1 + 65536, cb32, l31, kh, c32);
    __syncthreads();
    epi32_split<2>(c32, pb1, cb32, l31, kh, &Ch[0][0], &Cl[0][0], 264);
    __syncthreads();

    // proj2 -> out (32x32)
    gemm32_tile<256, 256>(&Ch[0][0], &Cl[0][0], 264, wp + OFF_PW2, wp + OFF_PW2 + 65536, cb32, l31, kh, c32);
    {
        int col = cb32 + l31;
        float bb = pb2[col];
#pragma unroll
        for (int r = 0; r < 16; ++r) {
            int lrow = (r & 3) + 8 * (r >> 2) + 4 * kh;
            int row = row0 + lrow;
            if (row < M) out[(size_t)row * 256 + col] = c32[r] + bb;
        }
    }
}

// ---------------------------------------------------------------------------
// prep: blocks 0..63 compute M3 = iW3@aW1; block 64 computes c3 = ib3@aW1
// ---------------------------------------------------------------------------
__global__ void mc3_kernel(const float* __restrict__ iW3, const float* __restrict__ aW1,
                           const float* __restrict__ ib3, float* __restrict__ m3f,
                           float* __restrict__ c3f)
{
    int b = blockIdx.x;
    if (b < 64) {
        int idx = b * 256 + threadIdx.x;    // 16384
        int k = idx >> 7, j = idx & 127;
        float s = 0.f;
        for (int t = 0; t < 256; ++t) s += iW3[k * 256 + t] * aW1[t * 128 + j];
        m3f[idx] = s;
    } else {
        int j = threadIdx.x;
        if (j < 128) {
            float s = 0.f;
            for (int t = 0; t < 256; ++t) s += ib3[t] * aW1[t * 128 + j];
            c3f[j] = s;
        }
    }
}

// fp32 W[K][Nc] -> split bf16 (hi,lo) in B-fragment order
__global__ void pack_all(const float* s0, const float* s1, const float* s2,
                         const float* s3, const float* s4, const float* s5,
                         const float* s6, const float* s7, const float* s8,
                         bf16_t* dst)
{
    const float* srcs[9] = {s0, s1, s2, s3, s4, s5, s6, s7, s8};
    const int lgN[9] = {7, 7, 8, 7, 7, 8, 8, 8, 7};
    const int sz[9]  = {32768, 16384, 32768, 32768, 16384, 32768, 65536, 65536, 16384};
    const int off[9] = {OFF_IW1, OFF_IW2, OFF_IW3, OFF_AW1, OFF_AW2, OFF_AW3,
                        OFF_PW1, OFF_PW2, OFF_M3};
    int m = blockIdx.y;
    int idx = blockIdx.x * blockDim.x + threadIdx.x;
    if (idx >= sz[m]) return;
    int lg = lgN[m];
    int Nc = 1 << lg;
    int k = idx >> lg;
    int n = idx & (Nc - 1);
    float w = srcs[m][idx];
    bf16_t hi = (bf16_t)w;
    bf16_t lo = (bf16_t)(w - (float)hi);
    int p = (((k >> 5) * 4 + ((k >> 3) & 3)) * Nc + n) * 8 + (k & 7);
    bf16_t* dh = dst + off[m];
    dh[p] = hi;
    dh[sz[m] + p] = lo;
}

// ---------------------------------------------------------------------------
// CSR build: 3-stage multi-block scan -> fill (count folded into kernelA)
// ---------------------------------------------------------------------------
__global__ void scan1(const int* __restrict__ cnt, int* __restrict__ offs,
                      int* __restrict__ bsum, int Nn)
{
    __shared__ int s[256];
    int tid = threadIdx.x;
    int g = blockIdx.x * 256 + tid;
    int v = (g < Nn) ? cnt[g] : 0;
    s[tid] = v;
    __syncthreads();
    for (int off = 1; off < 256; off <<= 1) {
        int u = (tid >= off) ? s[tid - off] : 0;
        __syncthreads();
        s[tid] += u;
        __syncthreads();
    }
    if (g < Nn) offs[g] = s[tid] - v;          // block-exclusive
    if (tid == 255) bsum[blockIdx.x] = s[255];
}

__global__ void scan2(int* __restrict__ bsum, int NB)
{
    __shared__ int s[256];
    int tid = threadIdx.x;
    if (NB > 256) {                            // safety fallback (unused at N=50k)
        if (tid == 0) {
            int run = 0;
            for (int i = 0; i < NB; ++i) { int v = bsum[i]; bsum[i] = run; run += v; }
        }
        return;
    }
    int v = (tid < NB) ? bsum[tid] : 0;
    s[tid] = v;
    __syncthreads();
    for (int off = 1; off < 256; off <<= 1) {
        int u = (tid >= off) ? s[tid - off] : 0;
        __syncthreads();
        s[tid] += u;
        __syncthreads();
    }
    if (tid < NB) bsum[tid] = s[tid] - v;      // exclusive block bases
}

__global__ void scan3(int* __restrict__ offs, const int* __restrict__ bsum,
                      int* __restrict__ cursor, int Nn)
{
    int g = blockIdx.x * 256 + threadIdx.x;
    if (g < Nn) {
        int o = offs[g] + bsum[blockIdx.x];
        offs[g] = o;
        cursor[g] = o;
    }
}

__global__ void fill_kernel(const int* __restrict__ dst, const int* __restrict__ src,
                            const int* __restrict__ r, int* __restrict__ cursor,
                            int* __restrict__ ridx, int E)
{
    int e = blockIdx.x * blockDim.x + threadIdx.x;
    if (e < E) {
        int p = atomicAdd(&cursor[dst[e]], 1);
        ridx[p] = src[e] * 2 + r[e];
    }
}

extern "C" void kernel_launch(void* const* d_in, const int* in_sizes, int n_in,
                              void* d_out, int out_size, void* d_ws, size_t ws_size,
                              hipStream_t stream)
{
    const float* h   = (const float*)d_in[0];
    const int* src   = (const int*)d_in[1];
    const int* dst   = (const int*)d_in[2];
    const int* r     = (const int*)d_in[3];
    const int* inv   = (const int*)d_in[4];
    const float* iW1 = (const float*)d_in[5];
    const float* ib1 = (const float*)d_in[6];
    const float* iW2 = (const float*)d_in[7];
    const float* ib2 = (const float*)d_in[8];
    const float* iW3 = (const float*)d_in[9];
    const float* ib3 = (const float*)d_in[10];
    const float* aW1 = (const float*)d_in[11];
    const float* ab1 = (const float*)d_in[12];
    const float* aW2 = (const float*)d_in[13];
    const float* ab2 = (const float*)d_in[14];
    const float* aW3 = (const float*)d_in[15];
    const float* ab3 = (const float*)d_in[16];
    const float* pW1 = (const float*)d_in[17];
    const float* pb1 = (const float*)d_in[18];
    const float* pW2 = (const float*)d_in[19];
    const float* pb2 = (const float*)d_in[20];

    const int N = in_sizes[0] / 256;
    const int E = in_sizes[1];
    float* out = (float*)d_out;

    // workspace carve-up
    f16_t* zbuf = (f16_t*)d_ws;                        // 2N*128 fp16 (z/zinv interleaved)
    int* cnt    = (int*)(zbuf + (size_t)2 * N * 128);  // N
    int* offs   = cnt + N;                             // N
    int* cursor = offs + N;                            // N
    int* bsum   = cursor + N;                          // 256
    int* ridx   = bsum + 256;                          // E
    bf16_t* wp  = (bf16_t*)(ridx + E);                 // WP_TOTAL packed bf16
    float* m3f  = (float*)(wp + WP_TOTAL);             // 16384
    float* c3f  = m3f + 16384;                         // 128

    (void)hipMemsetAsync(cnt, 0, (size_t)N * sizeof(int), stream);

    // 0) folded matrices + weight packing
    mc3_kernel<<<65, 256, 0, stream>>>(iW3, aW1, ib3, m3f, c3f);
    pack_all<<<dim3(256, 9), 256, 0, stream>>>(iW1, iW2, iW3, aW1, aW2, aW3,
                                               pW1, pW2, m3f, wp);

    const int tiles = (N + 31) / 32;
    const int EB = (E + 511) / 512;
    const int NB = (N + 255) / 256;

    // 1) per-node z / zinv (fp16) + fused CSR edge count
    kernelA<<<tiles + EB, 512, 0, stream>>>(h, zbuf, wp, ib1, ib2, c3f, N,
                                            tiles, dst, cnt, E);

    // 2) CSR scan + fill (ridx = src*2 + r)
    scan1<<<NB, 256, 0, stream>>>(cnt, offs, bsum, N);
    scan2<<<1, 256, 0, stream>>>(bsum, NB);
    scan3<<<NB, 256, 0, stream>>>(offs, bsum, cursor, N);
    fill_kernel<<<(E + 255) / 256, 256, 0, stream>>>(dst, src, r, cursor, ridx, E);

    // 3) fused: mean gather + L2a,L3a + cond inv-MLP + proj1,proj2
    kernelB<<<tiles, 512, 0, stream>>>(zbuf, ridx, offs, cnt, ab1, inv, out, wp,
                                       ab2, ab3, ib1, ib2, ib3, pb1, pb2, N);
}

// Round 3
// 391.402 us; speedup vs baseline: 1.0190x; 1.0074x over previous
//
#include <hip/hip_runtime.h>

typedef __bf16 bf16_t;
typedef _Float16 f16_t;
typedef f16_t f16x2 __attribute__((ext_vector_type(2)));
typedef f16_t f16x4 __attribute__((ext_vector_type(4)));
typedef bf16_t bf16x2 __attribute__((ext_vector_type(2)));
typedef bf16_t bf16x4 __attribute__((ext_vector_type(4)));
typedef bf16_t bf16x8 __attribute__((ext_vector_type(8)));
typedef float f32x4 __attribute__((ext_vector_type(4)));
typedef float f32x16 __attribute__((ext_vector_type(16)));

#define MFMA16(a, b, c) __builtin_amdgcn_mfma_f32_16x16x32_bf16(a, b, c, 0, 0, 0)
#define MFMA32(a, b, c) __builtin_amdgcn_mfma_f32_32x32x16_bf16(a, b, c, 0, 0, 0)

__device__ __forceinline__ float leaky01(float v) { return v >= 0.f ? v : 0.01f * v; }

// accumulate one f16x4 row fragment into 4 f32 sums.
// v_dot2_f32_f16 path: 4 VALU ops instead of 8 (cvt+add), identical numerics
// (products by 1.0/0.0 are exact, single f32 add rounding as before).
__device__ __forceinline__ void acc_f16x4(float& s0, float& s1, float& s2, float& s3,
                                          f16x4 v)
{
#if __has_builtin(__builtin_amdgcn_fdot2)
    const f16x2 K10 = (f16x2){(f16_t)1.0f, (f16_t)0.0f};
    const f16x2 K01 = (f16x2){(f16_t)0.0f, (f16_t)1.0f};
    f16x2 lo = (f16x2){v.x, v.y};
    f16x2 hi = (f16x2){v.z, v.w};
    s0 = __builtin_amdgcn_fdot2(lo, K10, s0, false);
    s1 = __builtin_amdgcn_fdot2(lo, K01, s1, false);
    s2 = __builtin_amdgcn_fdot2(hi, K10, s2, false);
    s3 = __builtin_amdgcn_fdot2(hi, K01, s3, false);
#else
    s0 += (float)v.x; s1 += (float)v.y; s2 += (float)v.z; s3 += (float)v.w;
#endif
}

// packed-weight offsets (bf16 elements): hi at OFF, lo at OFF+size
#define OFF_IW1 0         // 256x128
#define OFF_IW2 65536     // 128x128
#define OFF_IW3 98304     // 128x256
#define OFF_AW1 163840    // 256x128
#define OFF_AW2 229376    // 128x128
#define OFF_AW3 262144    // 128x256
#define OFF_PW1 327680    // 256x256
#define OFF_PW2 458752    // 256x256
#define OFF_M3  589824    // 128x128
#define WP_TOTAL 622592

// ---------------------------------------------------------------------------
// 16x16x32 GEMM tile: 32 rows x (NCT*16 cols per wave), K=KD, NC = out cols.
// ---------------------------------------------------------------------------
template<int KD, int NC, int NCT>
__device__ __forceinline__ void gemm_tile(
    const bf16_t* __restrict__ ah, const bf16_t* __restrict__ al, int sa,
    const bf16_t* __restrict__ Bh, const bf16_t* __restrict__ Bl,
    int cb, int qd, int ln, f32x4 (&acc)[2][4])
{
#pragma unroll
    for (int rt = 0; rt < 2; ++rt)
#pragma unroll
        for (int ct = 0; ct < NCT; ++ct) acc[rt][ct] = (f32x4){0.f, 0.f, 0.f, 0.f};
#pragma unroll
    for (int k0 = 0; k0 < KD; k0 += 32) {
        int ka = k0 + qd * 8;
        bf16x8 a0h = *(const bf16x8*)&ah[ln * sa + ka];
        bf16x8 a1h = *(const bf16x8*)&ah[(16 + ln) * sa + ka];
        bf16x8 a0l = *(const bf16x8*)&al[ln * sa + ka];
        bf16x8 a1l = *(const bf16x8*)&al[(16 + ln) * sa + ka];
#pragma unroll
        for (int ct = 0; ct < NCT; ++ct) {
            size_t bo = ((size_t)((k0 >> 5) * 4 + qd) * NC + cb + ct * 16 + ln) * 8;
            bf16x8 bh = *(const bf16x8*)(Bh + bo);
            bf16x8 bl = *(const bf16x8*)(Bl + bo);
            acc[0][ct] = MFMA16(a0h, bh, acc[0][ct]);
            acc[0][ct] = MFMA16(a0l, bh, acc[0][ct]);
            acc[0][ct] = MFMA16(a0h, bl, acc[0][ct]);
            acc[1][ct] = MFMA16(a1h, bh, acc[1][ct]);
            acc[1][ct] = MFMA16(a1l, bh, acc[1][ct]);
            acc[1][ct] = MFMA16(a1h, bl, acc[1][ct]);
        }
    }
}

// ---------------------------------------------------------------------------
// 32x32x16 GEMM tile: one 32x32 output tile per wave.
// ---------------------------------------------------------------------------
template<int KD, int NC>
__device__ __forceinline__ void gemm32_tile(
    const bf16_t* __restrict__ ah, const bf16_t* __restrict__ al, int sa,
    const bf16_t* __restrict__ Bh, const bf16_t* __restrict__ Bl,
    int cb, int l31, int kh, f32x16 &acc)
{
    f32x16 c0, c1;
#pragma unroll
    for (int i = 0; i < 16; ++i) { c0[i] = 0.f; c1[i] = 0.f; }
    const int arow = l31 * sa + kh * 8;
    const int bcol = cb + l31;
#pragma unroll
    for (int kc = 0; kc < KD; kc += 32) {
        bf16x8 ah0 = *(const bf16x8*)&ah[arow + kc];
        bf16x8 al0 = *(const bf16x8*)&al[arow + kc];
        bf16x8 ah1 = *(const bf16x8*)&ah[arow + kc + 16];
        bf16x8 al1 = *(const bf16x8*)&al[arow + kc + 16];
        size_t bo0 = ((size_t)((kc >> 3) + kh) * NC + bcol) * 8;
        size_t bo1 = ((size_t)((kc >> 3) + 2 + kh) * NC + bcol) * 8;
        bf16x8 bh0 = *(const bf16x8*)(Bh + bo0);
        bf16x8 bl0 = *(const bf16x8*)(Bl + bo0);
        bf16x8 bh1 = *(const bf16x8*)(Bh + bo1);
        bf16x8 bl1 = *(const bf16x8*)(Bl + bo1);
        c0 = MFMA32(ah0, bh0, c0);
        c1 = MFMA32(ah1, bh1, c1);
        c0 = MFMA32(al0, bh0, c0);
        c1 = MFMA32(al1, bh1, c1);
        c0 = MFMA32(ah0, bl0, c0);
        c1 = MFMA32(ah1, bl1, c1);
    }
    acc = c0 + c1;
}

// 16x16 epilogue -> split-bf16 LDS, act: 0 none, 1 leaky, 2 relu
template<int NCT>
__device__ __forceinline__ void epi_split(
    f32x4 (&acc)[2][4], const float* __restrict__ bias,
    int cb, int qd, int ln, bf16_t* dh, bf16_t* dl, int stride, int act)
{
#pragma unroll
    for (int ct = 0; ct < NCT; ++ct) {
        int col = cb + ct * 16 + ln;
        float bb = bias ? bias[col] : 0.f;
#pragma unroll
        for (int rt = 0; rt < 2; ++rt)
#pragma unroll
            for (int r = 0; r < 4; ++r) {
                float v = acc[rt][ct][r] + bb;
                if (act == 1) v = leaky01(v);
                else if (act == 2) v = fmaxf(v, 0.f);
                int row = rt * 16 + qd * 4 + r;
                bf16_t h = (bf16_t)v;
                dh[row * stride + col] = h;
                dl[row * stride + col] = (bf16_t)(v - (float)h);
            }
    }
}

// 32x32 epilogue -> split-bf16 LDS. C/D layout: col=lane&31,
// row=(reg&3)+8*(reg>>2)+4*(lane>>5).
template<int ACT>
__device__ __forceinline__ void epi32_split(
    const f32x16 &acc, const float* __restrict__ bias,
    int cb, int l31, int kh, bf16_t* dh, bf16_t* dl, int stride)
{
    int col = cb + l31;
    float bb = bias[col];
#pragma unroll
    for (int r = 0; r < 16; ++r) {
        float v = acc[r] + bb;
        if (ACT == 1) v = leaky01(v);
        else if (ACT == 2) v = fmaxf(v, 0.f);
        int row = (r & 3) + 8 * (r >> 2) + 4 * kh;
        bf16_t h = (bf16_t)v;
        dh[row * stride + col] = h;
        dl[row * stride + col] = (bf16_t)(v - (float)h);
    }
}

// ---------------------------------------------------------------------------
// kernelA: 512 thr / 32 rows. 32x32 split-dual: waves 0-3 z = h@aW1,
// waves 4-7 y1 = leaky(h@iW1+ib1). Then y2 = leaky(y1@iW2+ib2);
// zinv = y2@M3 + c3.  z,zinv (fp16) interleaved in zbuf.
// Extra blocks (blockIdx >= tiles) do the CSR edge count.
// ---------------------------------------------------------------------------
__global__ __launch_bounds__(512, 4) void kernelA(
    const float* __restrict__ h, f16_t* __restrict__ zbuf,
    const bf16_t* __restrict__ wp, const float* __restrict__ ib1,
    const float* __restrict__ ib2, const float* __restrict__ c3f, int M,
    int tiles, const int* __restrict__ dstE, int* __restrict__ cnt, int E)
{
    __shared__ bf16_t Xh[32][264], Xl[32][264];
    __shared__ bf16_t Yh[32][136], Yl[32][136];

    const int tid = threadIdx.x;

    if ((int)blockIdx.x >= tiles) {   // edge-count blocks
        int e = (blockIdx.x - tiles) * 512 + tid;
        if (e < E) atomicAdd(&cnt[dstE[e]], 1);
        return;
    }

    const int row0 = blockIdx.x * 32;
    const int lane = tid & 63;
    const int wv = tid >> 6;          // 0..7
    const int qd = lane >> 4;
    const int ln = lane & 15;
    const int cb = wv * 16;
    const int l31 = lane & 31;
    const int kh = lane >> 5;

    // stage h (32 x 256 fp32) -> split bf16
    {
        const float4* src4 = (const float4*)(h + (size_t)row0 * 256);
#pragma unroll
        for (int i = 0; i < 4; ++i) {
            int q = i * 512 + tid;
            int row = q >> 6;
            int kc = (q & 63) * 4;
            float4 v = make_float4(0.f, 0.f, 0.f, 0.f);
            if (row0 + row < M) v = src4[q];
            bf16_t h0 = (bf16_t)v.x; bf16_t l0 = (bf16_t)(v.x - (float)h0);
            bf16_t h1 = (bf16_t)v.y; bf16_t l1 = (bf16_t)(v.y - (float)h1);
            bf16_t h2 = (bf16_t)v.z; bf16_t l2 = (bf16_t)(v.z - (float)h2);
            bf16_t h3 = (bf16_t)v.w; bf16_t l3 = (bf16_t)(v.w - (float)h3);
            *(bf16x4*)&Xh[row][kc] = (bf16x4){h0, h1, h2, h3};
            *(bf16x4*)&Xl[row][kc] = (bf16x4){l0, l1, l2, l3};
        }
    }
    __syncthreads();

    // split-dual 32x32: waves 0-3 -> z (aW1), waves 4-7 -> y1 (iW1)
    {
        const bool isz = wv < 4;
        const int cb32 = (wv & 3) * 32;
        const bf16_t* Bh = wp + (isz ? OFF_AW1 : OFF_IW1);
        f32x16 a32;
        gemm32_tile<256, 128>(&Xh[0][0], &Xl[0][0], 264, Bh, Bh + 32768,
                              cb32, l31, kh, a32);
        int col = cb32 + l31;
        if (isz) {
#pragma unroll
            for (int r = 0; r < 16; ++r) {
                int lrow = (r & 3) + 8 * (r >> 2) + 4 * kh;
                int row = row0 + lrow;
                if (row < M) zbuf[((size_t)row * 2) * 128 + col] = (f16_t)a32[r];
            }
        } else {
            float bb = ib1[col];
#pragma unroll
            for (int r = 0; r < 16; ++r) {
                int lrow = (r & 3) + 8 * (r >> 2) + 4 * kh;
                float v = leaky01(a32[r] + bb);
                bf16_t hh = (bf16_t)v;
                Yh[lrow][col] = hh;
                Yl[lrow][col] = (bf16_t)(v - (float)hh);
            }
        }
    }
    __syncthreads();

    f32x4 acc[2][4];

    // y2 = leaky(y1@iW2 + ib2) -> X (h dead)
    gemm_tile<128, 128, 1>(&Yh[0][0], &Yl[0][0], 136, wp + OFF_IW2, wp + OFF_IW2 + 16384, cb, qd, ln, acc);
    epi_split<1>(acc, ib2, cb, qd, ln, &Xh[0][0], &Xl[0][0], 264, 1);
    __syncthreads();

    // zinv = y2 @ M3 + c3 -> zbuf odd rows (fp16)
    gemm_tile<128, 128, 1>(&Xh[0][0], &Xl[0][0], 264, wp + OFF_M3, wp + OFF_M3 + 16384, cb, qd, ln, acc);
    {
        int col = cb + ln;
        float bb = c3f[col];
#pragma unroll
        for (int rt = 0; rt < 2; ++rt)
#pragma unroll
            for (int r = 0; r < 4; ++r) {
                int row = row0 + rt * 16 + qd * 4 + r;
                if (row < M) zbuf[((size_t)row * 2 + 1) * 128 + col] = (f16_t)(acc[rt][0][r] + bb);
            }
    }
}

// ---------------------------------------------------------------------------
// kernelB: 512 thr / 32 rows. Phase 0 = mean gather, half-wave per node,
// dot2 accumulation. Narrow layers: 16x16 path. Wide layers: 32x32 path.
// ---------------------------------------------------------------------------
__global__ __launch_bounds__(512, 4) void kernelB(
    const f16_t* __restrict__ zbuf, const int* __restrict__ ridx,
    const int* __restrict__ offs, const int* __restrict__ cnt,
    const float* __restrict__ ab1, const int* __restrict__ invf,
    float* __restrict__ out, const bf16_t* __restrict__ wp,
    const float* __restrict__ ab2, const float* __restrict__ ab3,
    const float* __restrict__ ib1, const float* __restrict__ ib2,
    const float* __restrict__ ib3, const float* __restrict__ pb1,
    const float* __restrict__ pb2, int M)
{
    __shared__ bf16_t Ch[32][264], Cl[32][264];
    __shared__ bf16_t Ah[32][136], Al[32][136];
    __shared__ int sflag[32];

    const int tid = threadIdx.x;
    const int row0 = blockIdx.x * 32;
    const int lane = tid & 63;
    const int wv = tid >> 6;
    const int qd = lane >> 4;
    const int ln = lane & 15;
    const int cb2 = wv * 16;
    const int l31 = lane & 31;
    const int kh = lane >> 5;
    const int cb32 = wv * 32;

    // ---- phase 0: mean gather, half-wave (32 lanes x f16x4 = 256B row) per node
    const int hw = tid >> 5;          // half-wave 0..15
    const int hl = tid & 31;          // lane in half
    const int hbase = lane & 32;      // shfl base within wave
    const f16x4* zp4 = (const f16x4*)zbuf;   // row = 32 f16x4

#pragma unroll
    for (int pass = 0; pass < 2; ++pass) {
        int nl = pass * 16 + hw;
        int row = row0 + nl;
        float s0 = 0.f, s1 = 0.f, s2 = 0.f, s3 = 0.f;
        int c = 0;
        if (row < M) {
            int beg = offs[row];
            c = cnt[row];
            for (int base = 0; base < c; base += 32) {
                int rem = c - base; if (rem > 32) rem = 32;
                int myr = (hl < rem) ? ridx[beg + base + hl] : 0;
                int j = 0;
                for (; j + 16 <= rem; j += 16) {
                    f16x4 v[16];
#pragma unroll
                    for (int i = 0; i < 16; ++i) {
                        int rr = __shfl(myr, hbase + j + i);
                        v[i] = zp4[(size_t)rr * 32 + hl];
                    }
#pragma unroll
                    for (int i = 0; i < 16; ++i)
                        acc_f16x4(s0, s1, s2, s3, v[i]);
                }
                for (; j + 8 <= rem; j += 8) {
                    f16x4 v[8];
#pragma unroll
                    for (int i = 0; i < 8; ++i) {
                        int rr = __shfl(myr, hbase + j + i);
                        v[i] = zp4[(size_t)rr * 32 + hl];
                    }
#pragma unroll
                    for (int i = 0; i < 8; ++i)
                        acc_f16x4(s0, s1, s2, s3, v[i]);
                }
                for (; j < rem; ++j) {
                    int rr = __shfl(myr, hbase + j);
                    f16x4 vv = zp4[(size_t)rr * 32 + hl];
                    acc_f16x4(s0, s1, s2, s3, vv);
                }
            }
        }
        float invc = 1.0f / fmaxf((float)c, 1.0f);
        float4 bv = *(const float4*)&ab1[hl * 4];
        float m0 = leaky01(s0 * invc + bv.x);
        float m1 = leaky01(s1 * invc + bv.y);
        float m2 = leaky01(s2 * invc + bv.z);
        float m3 = leaky01(s3 * invc + bv.w);
        bf16_t h0 = (bf16_t)m0; bf16_t l0 = (bf16_t)(m0 - (float)h0);
        bf16_t h1 = (bf16_t)m1; bf16_t l1 = (bf16_t)(m1 - (float)h1);
        bf16_t h2 = (bf16_t)m2; bf16_t l2 = (bf16_t)(m2 - (float)h2);
        bf16_t h3 = (bf16_t)m3; bf16_t l3 = (bf16_t)(m3 - (float)h3);
        *(bf16x4*)&Ah[nl][hl * 4] = (bf16x4){h0, h1, h2, h3};
        *(bf16x4*)&Al[nl][hl * 4] = (bf16x4){l0, l1, l2, l3};
    }
    if (tid < 32) {
        int rr = row0 + tid;
        sflag[tid] = (rr < M) ? invf[rr] : 0;
    }
    __syncthreads();

    f32x4 acc[2][4];
    f32x16 c32;

    // L2a: u = leaky(y@aW2 + ab2) -> A (in place)
    gemm_tile<128, 128, 1>(&Ah[0][0], &Al[0][0], 136, wp + OFF_AW2, wp + OFF_AW2 + 16384, cb2, qd, ln, acc);
    __syncthreads();
    epi_split<1>(acc, ab2, cb2, qd, ln, &Ah[0][0], &Al[0][0], 136, 1);
    __syncthreads();

    // L3a: res = u@aW3 + ab3 -> C   (32x32: 8 waves x 32 cols = 256)
    gemm32_tile<128, 256>(&Ah[0][0], &Al[0][0], 136, wp + OFF_AW3, wp + OFF_AW3 + 32768, cb32, l31, kh, c32);
    epi32_split<0>(c32, ab3, cb32, l31, kh, &Ch[0][0], &Cl[0][0], 264);
    __syncthreads();

    // inv layer1: t1 = leaky(res@iW1 + ib1) -> A
    gemm_tile<256, 128, 1>(&Ch[0][0], &Cl[0][0], 264, wp + OFF_IW1, wp + OFF_IW1 + 32768, cb2, qd, ln, acc);
    epi_split<1>(acc, ib1, cb2, qd, ln, &Ah[0][0], &Al[0][0], 136, 1);
    __syncthreads();

    // inv layer2: t2 = leaky(t1@iW2 + ib2) -> A (in place)
    gemm_tile<128, 128, 1>(&Ah[0][0], &Al[0][0], 136, wp + OFF_IW2, wp + OFF_IW2 + 16384, cb2, qd, ln, acc);
    __syncthreads();
    epi_split<1>(acc, ib2, cb2, qd, ln, &Ah[0][0], &Al[0][0], 136, 1);
    __syncthreads();

    // inv layer3: overwrite C rows where flag set  (32x32)
    gemm32_tile<128, 256>(&Ah[0][0], &Al[0][0], 136, wp + OFF_IW3, wp + OFF_IW3 + 32768, cb32, l31, kh, c32);
    {
        int col = cb32 + l31;
        float bb = ib3[col];
#pragma unroll
        for (int r = 0; r < 16; ++r) {
            int row = (r & 3) + 8 * (r >> 2) + 4 * kh;
            if (sflag[row] == 1) {
                float v = c32[r] + bb;
                bf16_t hh = (bf16_t)v;
                Ch[row][col] = hh;
                Cl[row][col] = (bf16_t)(v - (float)hh);
            }
        }
    }
    __syncthreads();

    // proj1: p1 = relu(sel@pW1 + pb1) -> C (in place, 32x32)
    gemm32_tile<256, 256>(&Ch[0][0], &Cl[0][0], 264, wp + OFF_PW1, wp + OFF_PW1 + 65536, cb32, l31, kh, c32);
    __syncthreads();
    epi32_split<2>(c32, pb1, cb32, l31, kh, &Ch[0][0], &Cl[0][0], 264);
    __syncthreads();

    // proj2 -> out (32x32)
    gemm32_tile<256, 256>(&Ch[0][0], &Cl[0][0], 264, wp + OFF_PW2, wp + OFF_PW2 + 65536, cb32, l31, kh, c32);
    {
        int col = cb32 + l31;
        float bb = pb2[col];
#pragma unroll
        for (int r = 0; r < 16; ++r) {
            int lrow = (r & 3) + 8 * (r >> 2) + 4 * kh;
            int row = row0 + lrow;
            if (row < M) out[(size_t)row * 256 + col] = c32[r] + bb;
        }
    }
}

// ---------------------------------------------------------------------------
// prep: blocks 0..63 compute M3 = iW3@aW1; block 64 computes c3 = ib3@aW1
// ---------------------------------------------------------------------------
__global__ void mc3_kernel(const float* __restrict__ iW3, const float* __restrict__ aW1,
                           const float* __restrict__ ib3, float* __restrict__ m3f,
                           float* __restrict__ c3f)
{
    int b = blockIdx.x;
    if (b < 64) {
        int idx = b * 256 + threadIdx.x;    // 16384
        int k = idx >> 7, j = idx & 127;
        float s = 0.f;
        for (int t = 0; t < 256; ++t) s += iW3[k * 256 + t] * aW1[t * 128 + j];
        m3f[idx] = s;
    } else {
        int j = threadIdx.x;
        if (j < 128) {
            float s = 0.f;
            for (int t = 0; t < 256; ++t) s += ib3[t] * aW1[t * 128 + j];
            c3f[j] = s;
        }
    }
}

// fp32 W[K][Nc] -> split bf16 (hi,lo) in B-fragment order
__global__ void pack_all(const float* s0, const float* s1, const float* s2,
                         const float* s3, const float* s4, const float* s5,
                         const float* s6, const float* s7, const float* s8,
                         bf16_t* dst)
{
    const float* srcs[9] = {s0, s1, s2, s3, s4, s5, s6, s7, s8};
    const int lgN[9] = {7, 7, 8, 7, 7, 8, 8, 8, 7};
    const int sz[9]  = {32768, 16384, 32768, 32768, 16384, 32768, 65536, 65536, 16384};
    const int off[9] = {OFF_IW1, OFF_IW2, OFF_IW3, OFF_AW1, OFF_AW2, OFF_AW3,
                        OFF_PW1, OFF_PW2, OFF_M3};
    int m = blockIdx.y;
    int idx = blockIdx.x * blockDim.x + threadIdx.x;
    if (idx >= sz[m]) return;
    int lg = lgN[m];
    int Nc = 1 << lg;
    int k = idx >> lg;
    int n = idx & (Nc - 1);
    float w = srcs[m][idx];
    bf16_t hi = (bf16_t)w;
    bf16_t lo = (bf16_t)(w - (float)hi);
    int p = (((k >> 5) * 4 + ((k >> 3) & 3)) * Nc + n) * 8 + (k & 7);
    bf16_t* dh = dst + off[m];
    dh[p] = hi;
    dh[sz[m] + p] = lo;
}

// ---------------------------------------------------------------------------
// CSR build: 3-stage multi-block scan -> fill (count folded into kernelA)
// ---------------------------------------------------------------------------
__global__ void scan1(const int* __restrict__ cnt, int* __restrict__ offs,
                      int* __restrict__ bsum, int Nn)
{
    __shared__ int s[256];
    int tid = threadIdx.x;
    int g = blockIdx.x * 256 + tid;
    int v = (g < Nn) ? cnt[g] : 0;
    s[tid] = v;
    __syncthreads();
    for (int off = 1; off < 256; off <<= 1) {
        int u = (tid >= off) ? s[tid - off] : 0;
        __syncthreads();
        s[tid] += u;
        __syncthreads();
    }
    if (g < Nn) offs[g] = s[tid] - v;          // block-exclusive
    if (tid == 255) bsum[blockIdx.x] = s[255];
}

__global__ void scan2(int* __restrict__ bsum, int NB)
{
    __shared__ int s[256];
    int tid = threadIdx.x;
    if (NB > 256) {                            // safety fallback (unused at N=50k)
        if (tid == 0) {
            int run = 0;
            for (int i = 0; i < NB; ++i) { int v = bsum[i]; bsum[i] = run; run += v; }
        }
        return;
    }
    int v = (tid < NB) ? bsum[tid] : 0;
    s[tid] = v;
    __syncthreads();
    for (int off = 1; off < 256; off <<= 1) {
        int u = (tid >= off) ? s[tid - off] : 0;
        __syncthreads();
        s[tid] += u;
        __syncthreads();
    }
    if (tid < NB) bsum[tid] = s[tid] - v;      // exclusive block bases
}

__global__ void scan3(int* __restrict__ offs, const int* __restrict__ bsum,
                      int* __restrict__ cursor, int Nn)
{
    int g = blockIdx.x * 256 + threadIdx.x;
    if (g < Nn) {
        int o = offs[g] + bsum[blockIdx.x];
        offs[g] = o;
        cursor[g] = o;
    }
}

__global__ void fill_kernel(const int* __restrict__ dst, const int* __restrict__ src,
                            const int* __restrict__ r, int* __restrict__ cursor,
                            int* __restrict__ ridx, int E)
{
    int e = blockIdx.x * blockDim.x + threadIdx.x;
    if (e < E) {
        int p = atomicAdd(&cursor[dst[e]], 1);
        ridx[p] = src[e] * 2 + r[e];
    }
}

extern "C" void kernel_launch(void* const* d_in, const int* in_sizes, int n_in,
                              void* d_out, int out_size, void* d_ws, size_t ws_size,
                              hipStream_t stream)
{
    const float* h   = (const float*)d_in[0];
    const int* src   = (const int*)d_in[1];
    const int* dst   = (const int*)d_in[2];
    const int* r     = (const int*)d_in[3];
    const int* inv   = (const int*)d_in[4];
    const float* iW1 = (const float*)d_in[5];
    const float* ib1 = (const float*)d_in[6];
    const float* iW2 = (const float*)d_in[7];
    const float* ib2 = (const float*)d_in[8];
    const float* iW3 = (const float*)d_in[9];
    const float* ib3 = (const float*)d_in[10];
    const float* aW1 = (const float*)d_in[11];
    const float* ab1 = (const float*)d_in[12];
    const float* aW2 = (const float*)d_in[13];
    const float* ab2 = (const float*)d_in[14];
    const float* aW3 = (const float*)d_in[15];
    const float* ab3 = (const float*)d_in[16];
    const float* pW1 = (const float*)d_in[17];
    const float* pb1 = (const float*)d_in[18];
    const float* pW2 = (const float*)d_in[19];
    const float* pb2 = (const float*)d_in[20];

    const int N = in_sizes[0] / 256;
    const int E = in_sizes[1];
    float* out = (float*)d_out;

    // workspace carve-up
    f16_t* zbuf = (f16_t*)d_ws;                        // 2N*128 fp16 (z/zinv interleaved)
    int* cnt    = (int*)(zbuf + (size_t)2 * N * 128);  // N
    int* offs   = cnt + N;                             // N
    int* cursor = offs + N;                            // N
    int* bsum   = cursor + N;                          // 256
    int* ridx   = bsum + 256;                          // E
    bf16_t* wp  = (bf16_t*)(ridx + E);                 // WP_TOTAL packed bf16
    float* m3f  = (float*)(wp + WP_TOTAL);             // 16384
    float* c3f  = m3f + 16384;                         // 128

    (void)hipMemsetAsync(cnt, 0, (size_t)N * sizeof(int), stream);

    // 0) folded matrices + weight packing
    mc3_kernel<<<65, 256, 0, stream>>>(iW3, aW1, ib3, m3f, c3f);
    pack_all<<<dim3(256, 9), 256, 0, stream>>>(iW1, iW2, iW3, aW1, aW2, aW3,
                                               pW1, pW2, m3f, wp);

    const int tiles = (N + 31) / 32;
    const int EB = (E + 511) / 512;
    const int NB = (N + 255) / 256;

    // 1) per-node z / zinv (fp16) + fused CSR edge count
    kernelA<<<tiles + EB, 512, 0, stream>>>(h, zbuf, wp, ib1, ib2, c3f, N,
                                            tiles, dst, cnt, E);

    // 2) CSR scan + fill (ridx = src*2 + r)
    scan1<<<NB, 256, 0, stream>>>(cnt, offs, bsum, N);
    scan2<<<1, 256, 0, stream>>>(bsum, NB);
    scan3<<<NB, 256, 0, stream>>>(offs, bsum, cursor, N);
    fill_kernel<<<(E + 255) / 256, 256, 0, stream>>>(dst, src, r, cursor, ridx, E);

    // 3) fused: mean gather + L2a,L3a + cond inv-MLP + proj1,proj2
    kernelB<<<tiles, 512, 0, stream>>>(zbuf, ridx, offs, cnt, ab1, inv, out, wp,
                                       ab2, ab3, ib1, ib2, ib3, pb1, pb2, N);
}

// Round 4
// 339.303 us; speedup vs baseline: 1.1755x; 1.1535x over previous
//
#include <hip/hip_runtime.h>

typedef _Float16 f16_t;
typedef f16_t f16x2 __attribute__((ext_vector_type(2)));
typedef f16_t f16x4 __attribute__((ext_vector_type(4)));
typedef f16_t f16x8 __attribute__((ext_vector_type(8)));
typedef float f32x4 __attribute__((ext_vector_type(4)));
typedef float f32x16 __attribute__((ext_vector_type(16)));

#define MFMA16H(a, b, c) __builtin_amdgcn_mfma_f32_16x16x32_f16(a, b, c, 0, 0, 0)
#define MFMA32H(a, b, c) __builtin_amdgcn_mfma_f32_32x32x16_f16(a, b, c, 0, 0, 0)

__device__ __forceinline__ float leaky01(float v) { return v >= 0.f ? v : 0.01f * v; }

// accumulate one f16x4 row fragment into 4 f32 sums via v_dot2_f32_f16
__device__ __forceinline__ void acc_f16x4(float& s0, float& s1, float& s2, float& s3,
                                          f16x4 v)
{
#if __has_builtin(__builtin_amdgcn_fdot2)
    const f16x2 K10 = (f16x2){(f16_t)1.0f, (f16_t)0.0f};
    const f16x2 K01 = (f16x2){(f16_t)0.0f, (f16_t)1.0f};
    f16x2 lo = (f16x2){v.x, v.y};
    f16x2 hi = (f16x2){v.z, v.w};
    s0 = __builtin_amdgcn_fdot2(lo, K10, s0, false);
    s1 = __builtin_amdgcn_fdot2(lo, K01, s1, false);
    s2 = __builtin_amdgcn_fdot2(hi, K10, s2, false);
    s3 = __builtin_amdgcn_fdot2(hi, K01, s3, false);
#else
    s0 += (float)v.x; s1 += (float)v.y; s2 += (float)v.z; s3 += (float)v.w;
#endif
}

// packed-weight offsets (f16 elements, single precision — no hi/lo split)
#define OFF_IW1 0         // 256x128
#define OFF_IW2 32768     // 128x128
#define OFF_IW3 49152     // 128x256
#define OFF_AW1 81920     // 256x128
#define OFF_AW2 114688    // 128x128
#define OFF_AW3 131072    // 128x256
#define OFF_PW1 163840    // 256x256
#define OFF_PW2 229376    // 256x256
#define OFF_M3  294912    // 128x128
#define WP_TOTAL 311296

// ---------------------------------------------------------------------------
// Narrow (128-col) GEMM, 64 rows: 8 waves x 16 cols, 4 row-tiles of 16.
// One B-load feeds 4 MFMA16 -> 0.25 KB of B per MFMA.
// ---------------------------------------------------------------------------
template<int KD, int NC>
__device__ __forceinline__ void gemm16(
    const f16_t* __restrict__ a, int sa, const f16_t* __restrict__ B,
    int cb, int qd, int ln, f32x4 (&acc)[4])
{
#pragma unroll
    for (int rt = 0; rt < 4; ++rt) acc[rt] = (f32x4){0.f, 0.f, 0.f, 0.f};
#pragma unroll
    for (int k0 = 0; k0 < KD; k0 += 32) {
        int ka = k0 + qd * 8;
        f16x8 b = *(const f16x8*)(B + ((size_t)((k0 >> 5) * 4 + qd) * NC + cb + ln) * 8);
        f16x8 a0 = *(const f16x8*)&a[ln * sa + ka];
        f16x8 a1 = *(const f16x8*)&a[(16 + ln) * sa + ka];
        f16x8 a2 = *(const f16x8*)&a[(32 + ln) * sa + ka];
        f16x8 a3 = *(const f16x8*)&a[(48 + ln) * sa + ka];
        acc[0] = MFMA16H(a0, b, acc[0]);
        acc[1] = MFMA16H(a1, b, acc[1]);
        acc[2] = MFMA16H(a2, b, acc[2]);
        acc[3] = MFMA16H(a3, b, acc[3]);
    }
}

// ---------------------------------------------------------------------------
// Wide GEMM, 64 rows: per wave 32 cols x 2 row-subtiles of 32.
// Per K=32 chunk: 2 B-loads feed 4 MFMA32 -> 0.5 KB of B per MFMA.
// ---------------------------------------------------------------------------
template<int KD, int NC>
__device__ __forceinline__ void gemm32(
    const f16_t* __restrict__ a, int sa, const f16_t* __restrict__ B,
    int cb, int l31, int kh, f32x16 &o0, f32x16 &o1)
{
    f32x16 c0, c1;
#pragma unroll
    for (int i = 0; i < 16; ++i) { c0[i] = 0.f; c1[i] = 0.f; }
    const int ar0 = l31 * sa + kh * 8;
    const int ar1 = (32 + l31) * sa + kh * 8;
    const int bcol = cb + l31;
#pragma unroll
    for (int kc = 0; kc < KD; kc += 32) {
        f16x8 b0 = *(const f16x8*)(B + ((size_t)((kc >> 3) + kh) * NC + bcol) * 8);
        f16x8 b1 = *(const f16x8*)(B + ((size_t)((kc >> 3) + 2 + kh) * NC + bcol) * 8);
        f16x8 a00 = *(const f16x8*)&a[ar0 + kc];
        f16x8 a01 = *(const f16x8*)&a[ar0 + kc + 16];
        f16x8 a10 = *(const f16x8*)&a[ar1 + kc];
        f16x8 a11 = *(const f16x8*)&a[ar1 + kc + 16];
        c0 = MFMA32H(a00, b0, c0);
        c1 = MFMA32H(a10, b0, c1);
        c0 = MFMA32H(a01, b1, c0);
        c1 = MFMA32H(a11, b1, c1);
    }
    o0 = c0; o1 = c1;
}

// narrow epilogue -> f16 LDS. act: 0 none, 1 leaky, 2 relu
template<int ACT>
__device__ __forceinline__ void epi16(
    f32x4 (&acc)[4], const float* __restrict__ bias,
    int cb, int qd, int ln, f16_t* d, int stride)
{
    int col = cb + ln;
    float bb = bias[col];
#pragma unroll
    for (int rt = 0; rt < 4; ++rt)
#pragma unroll
        for (int r = 0; r < 4; ++r) {
            float v = acc[rt][r] + bb;
            if (ACT == 1) v = leaky01(v);
            else if (ACT == 2) v = fmaxf(v, 0.f);
            d[(rt * 16 + qd * 4 + r) * stride + col] = (f16_t)v;
        }
}

// wide epilogue -> f16 LDS. C/D layout: col=lane&31, row=(r&3)+8*(r>>2)+4*kh.
template<int ACT>
__device__ __forceinline__ void epi32(
    const f32x16 &a0, const f32x16 &a1, const float* __restrict__ bias,
    int cb, int l31, int kh, f16_t* d, int stride)
{
    int col = cb + l31;
    float bb = bias[col];
#pragma unroll
    for (int r = 0; r < 16; ++r) {
        float v0 = a0[r] + bb;
        float v1 = a1[r] + bb;
        if (ACT == 1) { v0 = leaky01(v0); v1 = leaky01(v1); }
        else if (ACT == 2) { v0 = fmaxf(v0, 0.f); v1 = fmaxf(v1, 0.f); }
        int row = (r & 3) + 8 * (r >> 2) + 4 * kh;
        d[row * stride + col] = (f16_t)v0;
        d[(32 + row) * stride + col] = (f16_t)v1;
    }
}

// ---------------------------------------------------------------------------
// kernelA: 512 thr / 64 rows. Dual wide: waves 0-3 z = h@aW1, waves 4-7
// y1 = leaky(h@iW1+ib1). Then y2 = leaky(y1@iW2+ib2); zinv = y2@M3 + c3.
// z,zinv (f16) interleaved in zbuf. Extra blocks do the CSR edge count.
// ---------------------------------------------------------------------------
__global__ __launch_bounds__(512, 4) void kernelA(
    const float* __restrict__ h, f16_t* __restrict__ zbuf,
    const f16_t* __restrict__ wp, const float* __restrict__ ib1,
    const float* __restrict__ ib2, const float* __restrict__ c3f, int M,
    int tiles, const int* __restrict__ dstE, int* __restrict__ cnt, int E)
{
    __shared__ f16_t X[64][264];
    __shared__ f16_t Y[64][136];

    const int tid = threadIdx.x;

    if ((int)blockIdx.x >= tiles) {   // edge-count blocks
        int e = (blockIdx.x - tiles) * 512 + tid;
        if (e < E) atomicAdd(&cnt[dstE[e]], 1);
        return;
    }

    const int row0 = blockIdx.x * 64;
    const int lane = tid & 63;
    const int wv = tid >> 6;          // 0..7
    const int qd = lane >> 4;
    const int ln = lane & 15;
    const int cb = wv * 16;
    const int l31 = lane & 31;
    const int kh = lane >> 5;

    // stage h (64 x 256 fp32) -> f16
    {
        const float4* src4 = (const float4*)(h + (size_t)row0 * 256);
#pragma unroll
        for (int i = 0; i < 8; ++i) {
            int q = i * 512 + tid;
            int row = q >> 6;
            int kc = (q & 63) * 4;
            float4 v = make_float4(0.f, 0.f, 0.f, 0.f);
            if (row0 + row < M) v = src4[q];
            *(f16x4*)&X[row][kc] = (f16x4){(f16_t)v.x, (f16_t)v.y, (f16_t)v.z, (f16_t)v.w};
        }
    }
    __syncthreads();

    // dual wide: waves 0-3 -> z (aW1), waves 4-7 -> y1 (iW1); 32 cols/wave
    {
        const bool isz = wv < 4;
        const int cb32 = (wv & 3) * 32;
        const f16_t* Bw = wp + (isz ? OFF_AW1 : OFF_IW1);
        f32x16 z0, z1;
        gemm32<256, 128>(&X[0][0], 264, Bw, cb32, l31, kh, z0, z1);
        int col = cb32 + l31;
        if (isz) {
#pragma unroll
            for (int r = 0; r < 16; ++r) {
                int lrow = (r & 3) + 8 * (r >> 2) + 4 * kh;
                int row = row0 + lrow;
                if (row < M) zbuf[((size_t)row * 2) * 128 + col] = (f16_t)z0[r];
                row += 32;
                if (row < M) zbuf[((size_t)row * 2) * 128 + col] = (f16_t)z1[r];
            }
        } else {
            float bb = ib1[col];
#pragma unroll
            for (int r = 0; r < 16; ++r) {
                int lrow = (r & 3) + 8 * (r >> 2) + 4 * kh;
                Y[lrow][col] = (f16_t)leaky01(z0[r] + bb);
                Y[32 + lrow][col] = (f16_t)leaky01(z1[r] + bb);
            }
        }
    }
    __syncthreads();

    f32x4 a4[4];

    // y2 = leaky(y1@iW2 + ib2) -> X (h dead)
    gemm16<128, 128>(&Y[0][0], 136, wp + OFF_IW2, cb, qd, ln, a4);
    epi16<1>(a4, ib2, cb, qd, ln, &X[0][0], 264);
    __syncthreads();

    // zinv = y2 @ M3 + c3 -> zbuf odd rows (f16)
    gemm16<128, 128>(&X[0][0], 264, wp + OFF_M3, cb, qd, ln, a4);
    {
        int col = cb + ln;
        float bb = c3f[col];
#pragma unroll
        for (int rt = 0; rt < 4; ++rt)
#pragma unroll
            for (int r = 0; r < 4; ++r) {
                int row = row0 + rt * 16 + qd * 4 + r;
                if (row < M) zbuf[((size_t)row * 2 + 1) * 128 + col] = (f16_t)(a4[rt][r] + bb);
            }
    }
}

// ---------------------------------------------------------------------------
// kernelB: 512 thr / 64 rows. Phase 0 = mean gather (half-wave per node,
// 4 passes). Narrow layers: gemm16. Wide layers: gemm32.
// ---------------------------------------------------------------------------
__global__ __launch_bounds__(512, 4) void kernelB(
    const f16_t* __restrict__ zbuf, const int* __restrict__ ridx,
    const int* __restrict__ offs, const int* __restrict__ cnt,
    const float* __restrict__ ab1, const int* __restrict__ invf,
    float* __restrict__ out, const f16_t* __restrict__ wp,
    const float* __restrict__ ab2, const float* __restrict__ ab3,
    const float* __restrict__ ib1, const float* __restrict__ ib2,
    const float* __restrict__ ib3, const float* __restrict__ pb1,
    const float* __restrict__ pb2, int M)
{
    __shared__ f16_t C[64][264];
    __shared__ f16_t A[64][136];
    __shared__ int sflag[64];

    const int tid = threadIdx.x;
    const int row0 = blockIdx.x * 64;
    const int lane = tid & 63;
    const int wv = tid >> 6;
    const int qd = lane >> 4;
    const int ln = lane & 15;
    const int cb2 = wv * 16;
    const int l31 = lane & 31;
    const int kh = lane >> 5;
    const int cb32 = wv * 32;

    // ---- phase 0: mean gather, half-wave (32 lanes x f16x4 = 256B row) per node
    const int hw = tid >> 5;          // half-wave 0..15
    const int hl = tid & 31;          // lane in half
    const int hbase = lane & 32;      // shfl base within wave
    const f16x4* zp4 = (const f16x4*)zbuf;   // row = 32 f16x4

#pragma unroll
    for (int pass = 0; pass < 4; ++pass) {
        int nl = pass * 16 + hw;
        int row = row0 + nl;
        float s0 = 0.f, s1 = 0.f, s2 = 0.f, s3 = 0.f;
        int c = 0;
        if (row < M) {
            int beg = offs[row];
            c = cnt[row];
            for (int base = 0; base < c; base += 32) {
                int rem = c - base; if (rem > 32) rem = 32;
                int myr = (hl < rem) ? ridx[beg + base + hl] : 0;
                int j = 0;
                for (; j + 16 <= rem; j += 16) {
                    f16x4 v[16];
#pragma unroll
                    for (int i = 0; i < 16; ++i) {
                        int rr = __shfl(myr, hbase + j + i);
                        v[i] = zp4[(size_t)rr * 32 + hl];
                    }
#pragma unroll
                    for (int i = 0; i < 16; ++i)
                        acc_f16x4(s0, s1, s2, s3, v[i]);
                }
                for (; j + 8 <= rem; j += 8) {
                    f16x4 v[8];
#pragma unroll
                    for (int i = 0; i < 8; ++i) {
                        int rr = __shfl(myr, hbase + j + i);
                        v[i] = zp4[(size_t)rr * 32 + hl];
                    }
#pragma unroll
                    for (int i = 0; i < 8; ++i)
                        acc_f16x4(s0, s1, s2, s3, v[i]);
                }
                for (; j < rem; ++j) {
                    int rr = __shfl(myr, hbase + j);
                    f16x4 vv = zp4[(size_t)rr * 32 + hl];
                    acc_f16x4(s0, s1, s2, s3, vv);
                }
            }
        }
        float invc = 1.0f / fmaxf((float)c, 1.0f);
        float4 bv = *(const float4*)&ab1[hl * 4];
        float m0 = leaky01(s0 * invc + bv.x);
        float m1 = leaky01(s1 * invc + bv.y);
        float m2 = leaky01(s2 * invc + bv.z);
        float m3 = leaky01(s3 * invc + bv.w);
        *(f16x4*)&A[nl][hl * 4] = (f16x4){(f16_t)m0, (f16_t)m1, (f16_t)m2, (f16_t)m3};
    }
    if (tid < 64) {
        int rr = row0 + tid;
        sflag[tid] = (rr < M) ? invf[rr] : 0;
    }
    __syncthreads();

    f32x4 a4[4];
    f32x16 c0, c1;

    // L2a: u = leaky(y@aW2 + ab2) -> A (in place)
    gemm16<128, 128>(&A[0][0], 136, wp + OFF_AW2, cb2, qd, ln, a4);
    __syncthreads();
    epi16<1>(a4, ab2, cb2, qd, ln, &A[0][0], 136);
    __syncthreads();

    // L3a: res = u@aW3 + ab3 -> C
    gemm32<128, 256>(&A[0][0], 136, wp + OFF_AW3, cb32, l31, kh, c0, c1);
    epi32<0>(c0, c1, ab3, cb32, l31, kh, &C[0][0], 264);
    __syncthreads();

    // inv layer1: t1 = leaky(res@iW1 + ib1) -> A
    gemm16<256, 128>(&C[0][0], 264, wp + OFF_IW1, cb2, qd, ln, a4);
    epi16<1>(a4, ib1, cb2, qd, ln, &A[0][0], 136);
    __syncthreads();

    // inv layer2: t2 = leaky(t1@iW2 + ib2) -> A (in place)
    gemm16<128, 128>(&A[0][0], 136, wp + OFF_IW2, cb2, qd, ln, a4);
    __syncthreads();
    epi16<1>(a4, ib2, cb2, qd, ln, &A[0][0], 136);
    __syncthreads();

    // inv layer3: overwrite C rows where flag set
    gemm32<128, 256>(&A[0][0], 136, wp + OFF_IW3, cb32, l31, kh, c0, c1);
    {
        int col = cb32 + l31;
        float bb = ib3[col];
#pragma unroll
        for (int r = 0; r < 16; ++r) {
            int lrow = (r & 3) + 8 * (r >> 2) + 4 * kh;
            if (sflag[lrow] == 1) C[lrow][col] = (f16_t)(c0[r] + bb);
            if (sflag[32 + lrow] == 1) C[32 + lrow][col] = (f16_t)(c1[r] + bb);
        }
    }
    __syncthreads();

    // proj1: p1 = relu(sel@pW1 + pb1) -> C (in place)
    gemm32<256, 256>(&C[0][0], 264, wp + OFF_PW1, cb32, l31, kh, c0, c1);
    __syncthreads();
    epi32<2>(c0, c1, pb1, cb32, l31, kh, &C[0][0], 264);
    __syncthreads();

    // proj2 -> out
    gemm32<256, 256>(&C[0][0], 264, wp + OFF_PW2, cb32, l31, kh, c0, c1);
    {
        int col = cb32 + l31;
        float bb = pb2[col];
#pragma unroll
        for (int r = 0; r < 16; ++r) {
            int lrow = (r & 3) + 8 * (r >> 2) + 4 * kh;
            int row = row0 + lrow;
            if (row < M) out[(size_t)row * 256 + col] = c0[r] + bb;
            row += 32;
            if (row < M) out[(size_t)row * 256 + col] = c1[r] + bb;
        }
    }
}

// ---------------------------------------------------------------------------
// prep: blocks 0..63 compute M3 = iW3@aW1; block 64 computes c3 = ib3@aW1
// ---------------------------------------------------------------------------
__global__ void mc3_kernel(const float* __restrict__ iW3, const float* __restrict__ aW1,
                           const float* __restrict__ ib3, float* __restrict__ m3f,
                           float* __restrict__ c3f)
{
    int b = blockIdx.x;
    if (b < 64) {
        int idx = b * 256 + threadIdx.x;    // 16384
        int k = idx >> 7, j = idx & 127;
        float s = 0.f;
        for (int t = 0; t < 256; ++t) s += iW3[k * 256 + t] * aW1[t * 128 + j];
        m3f[idx] = s;
    } else {
        int j = threadIdx.x;
        if (j < 128) {
            float s = 0.f;
            for (int t = 0; t < 256; ++t) s += ib3[t] * aW1[t * 128 + j];
            c3f[j] = s;
        }
    }
}

// fp32 W[K][Nc] -> f16 in B-fragment order: [k>>3][n][k&7]
__global__ void pack_all(const float* s0, const float* s1, const float* s2,
                         const float* s3, const float* s4, const float* s5,
                         const float* s6, const float* s7, const float* s8,
                         f16_t* dst)
{
    const float* srcs[9] = {s0, s1, s2, s3, s4, s5, s6, s7, s8};
    const int lgN[9] = {7, 7, 8, 7, 7, 8, 8, 8, 7};
    const int sz[9]  = {32768, 16384, 32768, 32768, 16384, 32768, 65536, 65536, 16384};
    const int off[9] = {OFF_IW1, OFF_IW2, OFF_IW3, OFF_AW1, OFF_AW2, OFF_AW3,
                        OFF_PW1, OFF_PW2, OFF_M3};
    int m = blockIdx.y;
    int idx = blockIdx.x * blockDim.x + threadIdx.x;
    if (idx >= sz[m]) return;
    int lg = lgN[m];
    int Nc = 1 << lg;
    int k = idx >> lg;
    int n = idx & (Nc - 1);
    int p = ((k >> 3) * Nc + n) * 8 + (k & 7);
    dst[off[m] + p] = (f16_t)srcs[m][idx];
}

// ---------------------------------------------------------------------------
// CSR build: 3-stage multi-block scan -> fill (count folded into kernelA)
// ---------------------------------------------------------------------------
__global__ void scan1(const int* __restrict__ cnt, int* __restrict__ offs,
                      int* __restrict__ bsum, int Nn)
{
    __shared__ int s[256];
    int tid = threadIdx.x;
    int g = blockIdx.x * 256 + tid;
    int v = (g < Nn) ? cnt[g] : 0;
    s[tid] = v;
    __syncthreads();
    for (int off = 1; off < 256; off <<= 1) {
        int u = (tid >= off) ? s[tid - off] : 0;
        __syncthreads();
        s[tid] += u;
        __syncthreads();
    }
    if (g < Nn) offs[g] = s[tid] - v;          // block-exclusive
    if (tid == 255) bsum[blockIdx.x] = s[255];
}

__global__ void scan2(int* __restrict__ bsum, int NB)
{
    __shared__ int s[256];
    int tid = threadIdx.x;
    if (NB > 256) {                            // safety fallback (unused at N=50k)
        if (tid == 0) {
            int run = 0;
            for (int i = 0; i < NB; ++i) { int v = bsum[i]; bsum[i] = run; run += v; }
        }
        return;
    }
    int v = (tid < NB) ? bsum[tid] : 0;
    s[tid] = v;
    __syncthreads();
    for (int off = 1; off < 256; off <<= 1) {
        int u = (tid >= off) ? s[tid - off] : 0;
        __syncthreads();
        s[tid] += u;
        __syncthreads();
    }
    if (tid < NB) bsum[tid] = s[tid] - v;      // exclusive block bases
}

__global__ void scan3(int* __restrict__ offs, const int* __restrict__ bsum,
                      int* __restrict__ cursor, int Nn)
{
    int g = blockIdx.x * 256 + threadIdx.x;
    if (g < Nn) {
        int o = offs[g] + bsum[blockIdx.x];
        offs[g] = o;
        cursor[g] = o;
    }
}

__global__ void fill_kernel(const int* __restrict__ dst, const int* __restrict__ src,
                            const int* __restrict__ r, int* __restrict__ cursor,
                            int* __restrict__ ridx, int E)
{
    int e = blockIdx.x * blockDim.x + threadIdx.x;
    if (e < E) {
        int p = atomicAdd(&cursor[dst[e]], 1);
        ridx[p] = src[e] * 2 + r[e];
    }
}

extern "C" void kernel_launch(void* const* d_in, const int* in_sizes, int n_in,
                              void* d_out, int out_size, void* d_ws, size_t ws_size,
                              hipStream_t stream)
{
    const float* h   = (const float*)d_in[0];
    const int* src   = (const int*)d_in[1];
    const int* dst   = (const int*)d_in[2];
    const int* r     = (const int*)d_in[3];
    const int* inv   = (const int*)d_in[4];
    const float* iW1 = (const float*)d_in[5];
    const float* ib1 = (const float*)d_in[6];
    const float* iW2 = (const float*)d_in[7];
    const float* ib2 = (const float*)d_in[8];
    const float* iW3 = (const float*)d_in[9];
    const float* ib3 = (const float*)d_in[10];
    const float* aW1 = (const float*)d_in[11];
    const float* ab1 = (const float*)d_in[12];
    const float* aW2 = (const float*)d_in[13];
    const float* ab2 = (const float*)d_in[14];
    const float* aW3 = (const float*)d_in[15];
    const float* ab3 = (const float*)d_in[16];
    const float* pW1 = (const float*)d_in[17];
    const float* pb1 = (const float*)d_in[18];
    const float* pW2 = (const float*)d_in[19];
    const float* pb2 = (const float*)d_in[20];

    const int N = in_sizes[0] / 256;
    const int E = in_sizes[1];
    float* out = (float*)d_out;

    // workspace carve-up
    f16_t* zbuf = (f16_t*)d_ws;                        // 2N*128 f16 (z/zinv interleaved)
    int* cnt    = (int*)(zbuf + (size_t)2 * N * 128);  // N
    int* offs   = cnt + N;                             // N
    int* cursor = offs + N;                            // N
    int* bsum   = cursor + N;                          // 256
    int* ridx   = bsum + 256;                          // E
    f16_t* wp   = (f16_t*)(ridx + E);                  // WP_TOTAL packed f16
    float* m3f  = (float*)(wp + WP_TOTAL);             // 16384
    float* c3f  = m3f + 16384;                         // 128

    (void)hipMemsetAsync(cnt, 0, (size_t)N * sizeof(int), stream);

    // 0) folded matrices + weight packing
    mc3_kernel<<<65, 256, 0, stream>>>(iW3, aW1, ib3, m3f, c3f);
    pack_all<<<dim3(256, 9), 256, 0, stream>>>(iW1, iW2, iW3, aW1, aW2, aW3,
                                               pW1, pW2, m3f, wp);

    const int tiles = (N + 63) / 64;
    const int EB = (E + 511) / 512;
    const int NB = (N + 255) / 256;

    // 1) per-node z / zinv (f16) + fused CSR edge count
    kernelA<<<tiles + EB, 512, 0, stream>>>(h, zbuf, wp, ib1, ib2, c3f, N,
                                            tiles, dst, cnt, E);

    // 2) CSR scan + fill (ridx = src*2 + r)
    scan1<<<NB, 256, 0, stream>>>(cnt, offs, bsum, N);
    scan2<<<1, 256, 0, stream>>>(bsum, NB);
    scan3<<<NB, 256, 0, stream>>>(offs, bsum, cursor, N);
    fill_kernel<<<(E + 255) / 256, 256, 0, stream>>>(dst, src, r, cursor, ridx, E);

    // 3) fused: mean gather + L2a,L3a + cond inv-MLP + proj1,proj2
    kernelB<<<tiles, 512, 0, stream>>>(zbuf, ridx, offs, cnt, ab1, inv, out, wp,
                                       ab2, ab3, ib1, ib2, ib3, pb1, pb2, N);
}

// Round 5
// 339.245 us; speedup vs baseline: 1.1757x; 1.0002x over previous
//
#include <hip/hip_runtime.h>

typedef _Float16 f16_t;
typedef f16_t f16x2 __attribute__((ext_vector_type(2)));
typedef f16_t f16x4 __attribute__((ext_vector_type(4)));
typedef f16_t f16x8 __attribute__((ext_vector_type(8)));
typedef float f32x4 __attribute__((ext_vector_type(4)));
typedef float f32x16 __attribute__((ext_vector_type(16)));

#define MFMA16H(a, b, c) __builtin_amdgcn_mfma_f32_16x16x32_f16(a, b, c, 0, 0, 0)
#define MFMA32H(a, b, c) __builtin_amdgcn_mfma_f32_32x32x16_f16(a, b, c, 0, 0, 0)

__device__ __forceinline__ float leaky01(float v) { return v >= 0.f ? v : 0.01f * v; }

// accumulate one f16x4 row fragment into 4 f32 sums via v_dot2_f32_f16
__device__ __forceinline__ void acc_f16x4(float& s0, float& s1, float& s2, float& s3,
                                          f16x4 v)
{
#if __has_builtin(__builtin_amdgcn_fdot2)
    const f16x2 K10 = (f16x2){(f16_t)1.0f, (f16_t)0.0f};
    const f16x2 K01 = (f16x2){(f16_t)0.0f, (f16_t)1.0f};
    f16x2 lo = (f16x2){v.x, v.y};
    f16x2 hi = (f16x2){v.z, v.w};
    s0 = __builtin_amdgcn_fdot2(lo, K10, s0, false);
    s1 = __builtin_amdgcn_fdot2(lo, K01, s1, false);
    s2 = __builtin_amdgcn_fdot2(hi, K10, s2, false);
    s3 = __builtin_amdgcn_fdot2(hi, K01, s3, false);
#else
    s0 += (float)v.x; s1 += (float)v.y; s2 += (float)v.z; s3 += (float)v.w;
#endif
}

// packed-weight offsets (f16 elements)
#define OFF_IW1 0         // 256x128
#define OFF_IW2 32768     // 128x128
#define OFF_IW3 49152     // 128x256
#define OFF_AW1 81920     // 256x128
#define OFF_AW2 114688    // 128x128
#define OFF_AW3 131072    // 128x256
#define OFF_PW1 163840    // 256x256
#define OFF_PW2 229376    // 256x256
#define OFF_M3  294912    // 128x128
#define WP_TOTAL 311296

// ---------------------------------------------------------------------------
// Narrow (128-col) GEMM, 64 rows: 8 waves x 16 cols, 4 row-tiles of 16.
// ---------------------------------------------------------------------------
template<int KD, int NC>
__device__ __forceinline__ void gemm16(
    const f16_t* __restrict__ a, int sa, const f16_t* __restrict__ B,
    int cb, int qd, int ln, f32x4 (&acc)[4])
{
#pragma unroll
    for (int rt = 0; rt < 4; ++rt) acc[rt] = (f32x4){0.f, 0.f, 0.f, 0.f};
#pragma unroll
    for (int k0 = 0; k0 < KD; k0 += 32) {
        int ka = k0 + qd * 8;
        f16x8 b = *(const f16x8*)(B + ((size_t)((k0 >> 5) * 4 + qd) * NC + cb + ln) * 8);
        f16x8 a0 = *(const f16x8*)&a[ln * sa + ka];
        f16x8 a1 = *(const f16x8*)&a[(16 + ln) * sa + ka];
        f16x8 a2 = *(const f16x8*)&a[(32 + ln) * sa + ka];
        f16x8 a3 = *(const f16x8*)&a[(48 + ln) * sa + ka];
        acc[0] = MFMA16H(a0, b, acc[0]);
        acc[1] = MFMA16H(a1, b, acc[1]);
        acc[2] = MFMA16H(a2, b, acc[2]);
        acc[3] = MFMA16H(a3, b, acc[3]);
    }
}

// ---------------------------------------------------------------------------
// Wide GEMM, 64 rows: per wave 32 cols x 2 row-subtiles of 32.
// ---------------------------------------------------------------------------
template<int KD, int NC>
__device__ __forceinline__ void gemm32(
    const f16_t* __restrict__ a, int sa, const f16_t* __restrict__ B,
    int cb, int l31, int kh, f32x16 &o0, f32x16 &o1)
{
    f32x16 c0, c1;
#pragma unroll
    for (int i = 0; i < 16; ++i) { c0[i] = 0.f; c1[i] = 0.f; }
    const int ar0 = l31 * sa + kh * 8;
    const int ar1 = (32 + l31) * sa + kh * 8;
    const int bcol = cb + l31;
#pragma unroll
    for (int kc = 0; kc < KD; kc += 32) {
        f16x8 b0 = *(const f16x8*)(B + ((size_t)((kc >> 3) + kh) * NC + bcol) * 8);
        f16x8 b1 = *(const f16x8*)(B + ((size_t)((kc >> 3) + 2 + kh) * NC + bcol) * 8);
        f16x8 a00 = *(const f16x8*)&a[ar0 + kc];
        f16x8 a01 = *(const f16x8*)&a[ar0 + kc + 16];
        f16x8 a10 = *(const f16x8*)&a[ar1 + kc];
        f16x8 a11 = *(const f16x8*)&a[ar1 + kc + 16];
        c0 = MFMA32H(a00, b0, c0);
        c1 = MFMA32H(a10, b0, c1);
        c0 = MFMA32H(a01, b1, c0);
        c1 = MFMA32H(a11, b1, c1);
    }
    o0 = c0; o1 = c1;
}

// narrow epilogue -> f16 LDS. act: 0 none, 1 leaky, 2 relu
template<int ACT>
__device__ __forceinline__ void epi16(
    f32x4 (&acc)[4], const float* __restrict__ bias,
    int cb, int qd, int ln, f16_t* d, int stride)
{
    int col = cb + ln;
    float bb = bias[col];
#pragma unroll
    for (int rt = 0; rt < 4; ++rt)
#pragma unroll
        for (int r = 0; r < 4; ++r) {
            float v = acc[rt][r] + bb;
            if (ACT == 1) v = leaky01(v);
            else if (ACT == 2) v = fmaxf(v, 0.f);
            d[(rt * 16 + qd * 4 + r) * stride + col] = (f16_t)v;
        }
}

// wide epilogue -> f16 LDS. C/D layout: col=lane&31, row=(r&3)+8*(r>>2)+4*kh.
template<int ACT>
__device__ __forceinline__ void epi32(
    const f32x16 &a0, const f32x16 &a1, const float* __restrict__ bias,
    int cb, int l31, int kh, f16_t* d, int stride)
{
    int col = cb + l31;
    float bb = bias[col];
#pragma unroll
    for (int r = 0; r < 16; ++r) {
        float v0 = a0[r] + bb;
        float v1 = a1[r] + bb;
        if (ACT == 1) { v0 = leaky01(v0); v1 = leaky01(v1); }
        else if (ACT == 2) { v0 = fmaxf(v0, 0.f); v1 = fmaxf(v1, 0.f); }
        int row = (r & 3) + 8 * (r >> 2) + 4 * kh;
        d[row * stride + col] = (f16_t)v0;
        d[(32 + row) * stride + col] = (f16_t)v1;
    }
}

// ---------------------------------------------------------------------------
// kernelA: 512 thr / 64 rows. Dual wide: waves 0-3 z = h@aW1, waves 4-7
// y1 = leaky(h@iW1+ib1). Then y2 = leaky(y1@iW2+ib2); zinv = y2@M3 + c3.
// z is staged into the dead half of X, zinv into dead Y, then one fully
// coalesced copy phase writes zbuf (node-major: [z(128)|zinv(128)] f16).
// Extra blocks (blockIdx >= tiles) do the CSR edge count.
// ---------------------------------------------------------------------------
__global__ __launch_bounds__(512, 4) void kernelA(
    const float* __restrict__ h, f16_t* __restrict__ zbuf,
    const f16_t* __restrict__ wp, const float* __restrict__ ib1,
    const float* __restrict__ ib2, const float* __restrict__ c3f, int M,
    int tiles, const int* __restrict__ dstE, int* __restrict__ cnt, int E)
{
    __shared__ f16_t X[64][264];
    __shared__ f16_t Y[64][136];

    const int tid = threadIdx.x;

    if ((int)blockIdx.x >= tiles) {   // edge-count blocks
        int e = (blockIdx.x - tiles) * 512 + tid;
        if (e < E) atomicAdd(&cnt[dstE[e]], 1);
        return;
    }

    const int row0 = blockIdx.x * 64;
    const int lane = tid & 63;
    const int wv = tid >> 6;          // 0..7
    const int qd = lane >> 4;
    const int ln = lane & 15;
    const int cb = wv * 16;
    const int l31 = lane & 31;
    const int kh = lane >> 5;

    // stage h (64 x 256 fp32) -> f16
    {
        const float4* src4 = (const float4*)(h + (size_t)row0 * 256);
#pragma unroll
        for (int i = 0; i < 8; ++i) {
            int q = i * 512 + tid;
            int row = q >> 6;
            int kc = (q & 63) * 4;
            float4 v = make_float4(0.f, 0.f, 0.f, 0.f);
            if (row0 + row < M) v = src4[q];
            *(f16x4*)&X[row][kc] = (f16x4){(f16_t)v.x, (f16_t)v.y, (f16_t)v.z, (f16_t)v.w};
        }
    }
    __syncthreads();

    // dual wide: waves 0-3 -> z (aW1), waves 4-7 -> y1 (iW1); 32 cols/wave
    {
        const bool isz = wv < 4;
        const int cb32 = (wv & 3) * 32;
        const f16_t* Bw = wp + (isz ? OFF_AW1 : OFF_IW1);
        f32x16 z0, z1;
        gemm32<256, 128>(&X[0][0], 264, Bw, cb32, l31, kh, z0, z1);
        __syncthreads();   // all waves done reading h -> X cols 128..256 reusable
        int col = cb32 + l31;
        if (isz) {
            // z -> X[:, 128+col]  (staged for the coalesced store)
#pragma unroll
            for (int r = 0; r < 16; ++r) {
                int lrow = (r & 3) + 8 * (r >> 2) + 4 * kh;
                X[lrow][128 + col] = (f16_t)z0[r];
                X[32 + lrow][128 + col] = (f16_t)z1[r];
            }
        } else {
            float bb = ib1[col];
#pragma unroll
            for (int r = 0; r < 16; ++r) {
                int lrow = (r & 3) + 8 * (r >> 2) + 4 * kh;
                Y[lrow][col] = (f16_t)leaky01(z0[r] + bb);
                Y[32 + lrow][col] = (f16_t)leaky01(z1[r] + bb);
            }
        }
    }
    __syncthreads();

    f32x4 a4[4];

    // y2 = leaky(y1@iW2 + ib2) -> X cols 0..128 (h dead; z untouched at 128..256)
    gemm16<128, 128>(&Y[0][0], 136, wp + OFF_IW2, cb, qd, ln, a4);
    epi16<1>(a4, ib2, cb, qd, ln, &X[0][0], 264);
    __syncthreads();

    // zinv = y2 @ M3 + c3 -> Y (y1 dead after the sync above)
    gemm16<128, 128>(&X[0][0], 264, wp + OFF_M3, cb, qd, ln, a4);
    {
        int col = cb + ln;
        float bb = c3f[col];
#pragma unroll
        for (int rt = 0; rt < 4; ++rt)
#pragma unroll
            for (int r = 0; r < 4; ++r)
                Y[rt * 16 + qd * 4 + r][col] = (f16_t)(a4[rt][r] + bb);
    }
    __syncthreads();

    // coalesced store: per node 512B contiguous = [z | zinv]
#pragma unroll
    for (int i = 0; i < 4; ++i) {
        int q = i * 512 + tid;
        int node = q >> 5;
        int seg = q & 31;
        int row = row0 + node;
        if (row < M) {
            f16x8 v = (seg < 16) ? *(const f16x8*)&X[node][128 + seg * 8]
                                 : *(const f16x8*)&Y[node][(seg - 16) * 8];
            *(f16x8*)&zbuf[(size_t)row * 256 + seg * 8] = v;
        }
    }
}

// ---------------------------------------------------------------------------
// kernelB: 512 thr / 64 rows. Phase 0 = mean gather (half-wave per node,
// 4 passes). Narrow layers: gemm16. Wide layers: gemm32.  (unchanged vs R4)
// ---------------------------------------------------------------------------
__global__ __launch_bounds__(512, 4) void kernelB(
    const f16_t* __restrict__ zbuf, const int* __restrict__ ridx,
    const int* __restrict__ offs, const int* __restrict__ cnt,
    const float* __restrict__ ab1, const int* __restrict__ invf,
    float* __restrict__ out, const f16_t* __restrict__ wp,
    const float* __restrict__ ab2, const float* __restrict__ ab3,
    const float* __restrict__ ib1, const float* __restrict__ ib2,
    const float* __restrict__ ib3, const float* __restrict__ pb1,
    const float* __restrict__ pb2, int M)
{
    __shared__ f16_t C[64][264];
    __shared__ f16_t A[64][136];
    __shared__ int sflag[64];

    const int tid = threadIdx.x;
    const int row0 = blockIdx.x * 64;
    const int lane = tid & 63;
    const int wv = tid >> 6;
    const int qd = lane >> 4;
    const int ln = lane & 15;
    const int cb2 = wv * 16;
    const int l31 = lane & 31;
    const int kh = lane >> 5;
    const int cb32 = wv * 32;

    // ---- phase 0: mean gather, half-wave (32 lanes x f16x4 = 256B row) per node
    const int hw = tid >> 5;          // half-wave 0..15
    const int hl = tid & 31;          // lane in half
    const int hbase = lane & 32;      // shfl base within wave
    const f16x4* zp4 = (const f16x4*)zbuf;   // row = 32 f16x4

#pragma unroll
    for (int pass = 0; pass < 4; ++pass) {
        int nl = pass * 16 + hw;
        int row = row0 + nl;
        float s0 = 0.f, s1 = 0.f, s2 = 0.f, s3 = 0.f;
        int c = 0;
        if (row < M) {
            int beg = offs[row];
            c = cnt[row];
            for (int base = 0; base < c; base += 32) {
                int rem = c - base; if (rem > 32) rem = 32;
                int myr = (hl < rem) ? ridx[beg + base + hl] : 0;
                int j = 0;
                for (; j + 16 <= rem; j += 16) {
                    f16x4 v[16];
#pragma unroll
                    for (int i = 0; i < 16; ++i) {
                        int rr = __shfl(myr, hbase + j + i);
                        v[i] = zp4[(size_t)rr * 32 + hl];
                    }
#pragma unroll
                    for (int i = 0; i < 16; ++i)
                        acc_f16x4(s0, s1, s2, s3, v[i]);
                }
                for (; j + 8 <= rem; j += 8) {
                    f16x4 v[8];
#pragma unroll
                    for (int i = 0; i < 8; ++i) {
                        int rr = __shfl(myr, hbase + j + i);
                        v[i] = zp4[(size_t)rr * 32 + hl];
                    }
#pragma unroll
                    for (int i = 0; i < 8; ++i)
                        acc_f16x4(s0, s1, s2, s3, v[i]);
                }
                for (; j < rem; ++j) {
                    int rr = __shfl(myr, hbase + j);
                    f16x4 vv = zp4[(size_t)rr * 32 + hl];
                    acc_f16x4(s0, s1, s2, s3, vv);
                }
            }
        }
        float invc = 1.0f / fmaxf((float)c, 1.0f);
        float4 bv = *(const float4*)&ab1[hl * 4];
        float m0 = leaky01(s0 * invc + bv.x);
        float m1 = leaky01(s1 * invc + bv.y);
        float m2 = leaky01(s2 * invc + bv.z);
        float m3 = leaky01(s3 * invc + bv.w);
        *(f16x4*)&A[nl][hl * 4] = (f16x4){(f16_t)m0, (f16_t)m1, (f16_t)m2, (f16_t)m3};
    }
    if (tid < 64) {
        int rr = row0 + tid;
        sflag[tid] = (rr < M) ? invf[rr] : 0;
    }
    __syncthreads();

    f32x4 a4[4];
    f32x16 c0, c1;

    // L2a: u = leaky(y@aW2 + ab2) -> A (in place)
    gemm16<128, 128>(&A[0][0], 136, wp + OFF_AW2, cb2, qd, ln, a4);
    __syncthreads();
    epi16<1>(a4, ab2, cb2, qd, ln, &A[0][0], 136);
    __syncthreads();

    // L3a: res = u@aW3 + ab3 -> C
    gemm32<128, 256>(&A[0][0], 136, wp + OFF_AW3, cb32, l31, kh, c0, c1);
    epi32<0>(c0, c1, ab3, cb32, l31, kh, &C[0][0], 264);
    __syncthreads();

    // inv layer1: t1 = leaky(res@iW1 + ib1) -> A
    gemm16<256, 128>(&C[0][0], 264, wp + OFF_IW1, cb2, qd, ln, a4);
    epi16<1>(a4, ib1, cb2, qd, ln, &A[0][0], 136);
    __syncthreads();

    // inv layer2: t2 = leaky(t1@iW2 + ib2) -> A (in place)
    gemm16<128, 128>(&A[0][0], 136, wp + OFF_IW2, cb2, qd, ln, a4);
    __syncthreads();
    epi16<1>(a4, ib2, cb2, qd, ln, &A[0][0], 136);
    __syncthreads();

    // inv layer3: overwrite C rows where flag set
    gemm32<128, 256>(&A[0][0], 136, wp + OFF_IW3, cb32, l31, kh, c0, c1);
    {
        int col = cb32 + l31;
        float bb = ib3[col];
#pragma unroll
        for (int r = 0; r < 16; ++r) {
            int lrow = (r & 3) + 8 * (r >> 2) + 4 * kh;
            if (sflag[lrow] == 1) C[lrow][col] = (f16_t)(c0[r] + bb);
            if (sflag[32 + lrow] == 1) C[32 + lrow][col] = (f16_t)(c1[r] + bb);
        }
    }
    __syncthreads();

    // proj1: p1 = relu(sel@pW1 + pb1) -> C (in place)
    gemm32<256, 256>(&C[0][0], 264, wp + OFF_PW1, cb32, l31, kh, c0, c1);
    __syncthreads();
    epi32<2>(c0, c1, pb1, cb32, l31, kh, &C[0][0], 264);
    __syncthreads();

    // proj2 -> out
    gemm32<256, 256>(&C[0][0], 264, wp + OFF_PW2, cb32, l31, kh, c0, c1);
    {
        int col = cb32 + l31;
        float bb = pb2[col];
#pragma unroll
        for (int r = 0; r < 16; ++r) {
            int lrow = (r & 3) + 8 * (r >> 2) + 4 * kh;
            int row = row0 + lrow;
            if (row < M) out[(size_t)row * 256 + col] = c0[r] + bb;
            row += 32;
            if (row < M) out[(size_t)row * 256 + col] = c1[r] + bb;
        }
    }
}

// ---------------------------------------------------------------------------
// pack_mc3: fp32 W[K][Nc] -> f16 in B-fragment order [k>>3][n][k&7].
// m==8 blocks compute M3 = iW3@aW1 on the fly (256-FMA per element) and
// block 64 of m==8 computes c3 = ib3@aW1.  (mc3_kernel folded in)
// ---------------------------------------------------------------------------
__global__ void pack_mc3(const float* s0, const float* s1, const float* s2,
                         const float* s3, const float* s4, const float* s5,
                         const float* s6, const float* s7,
                         const float* __restrict__ ib3, f16_t* dst,
                         float* __restrict__ c3f)
{
    int m = blockIdx.y;
    int bx = blockIdx.x;
    if (m == 8) {
        // M3 = iW3(128x256) @ aW1(256x128); pack to OFF_M3, Nc=128
        if (bx < 64) {
            int idx = bx * 256 + threadIdx.x;      // < 16384
            int k = idx >> 7, j = idx & 127;
            float s = 0.f;
            for (int t = 0; t < 256; ++t) s += s2[k * 256 + t] * s3[t * 128 + j];
            int p = ((k >> 3) * 128 + j) * 8 + (k & 7);
            dst[OFF_M3 + p] = (f16_t)s;
        } else if (bx == 64) {
            int j = threadIdx.x;
            if (j < 128) {
                float s = 0.f;
                for (int t = 0; t < 256; ++t) s += ib3[t] * s3[t * 128 + j];
                c3f[j] = s;
            }
        }
        return;
    }
    const float* srcs[8] = {s0, s1, s2, s3, s4, s5, s6, s7};
    const int lgN[8] = {7, 7, 8, 7, 7, 8, 8, 8};
    const int sz[8]  = {32768, 16384, 32768, 32768, 16384, 32768, 65536, 65536};
    const int off[8] = {OFF_IW1, OFF_IW2, OFF_IW3, OFF_AW1, OFF_AW2, OFF_AW3,
                        OFF_PW1, OFF_PW2};
    int idx = bx * blockDim.x + threadIdx.x;
    if (idx >= sz[m]) return;
    int lg = lgN[m];
    int Nc = 1 << lg;
    int k = idx >> lg;
    int n = idx & (Nc - 1);
    int p = ((k >> 3) * Nc + n) * 8 + (k & 7);
    dst[off[m] + p] = (f16_t)srcs[m][idx];
}

// ---------------------------------------------------------------------------
// CSR build: scan1 (block scans + block sums) -> scan3b (local re-scan of
// block sums, merged scan2) -> fill
// ---------------------------------------------------------------------------
__global__ void scan1(const int* __restrict__ cnt, int* __restrict__ offs,
                      int* __restrict__ bsum, int Nn)
{
    __shared__ int s[256];
    int tid = threadIdx.x;
    int g = blockIdx.x * 256 + tid;
    int v = (g < Nn) ? cnt[g] : 0;
    s[tid] = v;
    __syncthreads();
    for (int off = 1; off < 256; off <<= 1) {
        int u = (tid >= off) ? s[tid - off] : 0;
        __syncthreads();
        s[tid] += u;
        __syncthreads();
    }
    if (g < Nn) offs[g] = s[tid] - v;          // block-exclusive
    if (tid == 255) bsum[blockIdx.x] = s[255];
}

// requires NB <= 256 (true at N=50k: NB=196)
__global__ void scan3b(int* __restrict__ offs, const int* __restrict__ bsum,
                       int* __restrict__ cursor, int Nn, int NB)
{
    __shared__ int s[256];
    int tid = threadIdx.x;
    int bid = blockIdx.x;
    int v = (tid < NB) ? bsum[tid] : 0;
    s[tid] = v;
    __syncthreads();
    for (int off = 1; off < 256; off <<= 1) {
        int u = (tid >= off) ? s[tid - off] : 0;
        __syncthreads();
        s[tid] += u;
        __syncthreads();
    }
    int base = (bid > 0) ? s[bid - 1] : 0;     // sum of bsum[0..bid-1]
    int g = bid * 256 + tid;
    if (g < Nn) {
        int o = offs[g] + base;
        offs[g] = o;
        cursor[g] = o;
    }
}

// fallback path kernels (NB > 256; unused at N=50k)
__global__ void scan2(int* __restrict__ bsum, int NB)
{
    if (threadIdx.x == 0) {
        int run = 0;
        for (int i = 0; i < NB; ++i) { int v = bsum[i]; bsum[i] = run; run += v; }
    }
}

__global__ void scan3(int* __restrict__ offs, const int* __restrict__ bsum,
                      int* __restrict__ cursor, int Nn)
{
    int g = blockIdx.x * 256 + threadIdx.x;
    if (g < Nn) {
        int o = offs[g] + bsum[blockIdx.x];
        offs[g] = o;
        cursor[g] = o;
    }
}

__global__ void fill_kernel(const int* __restrict__ dst, const int* __restrict__ src,
                            const int* __restrict__ r, int* __restrict__ cursor,
                            int* __restrict__ ridx, int E)
{
    int e = blockIdx.x * blockDim.x + threadIdx.x;
    if (e < E) {
        int p = atomicAdd(&cursor[dst[e]], 1);
        ridx[p] = src[e] * 2 + r[e];
    }
}

extern "C" void kernel_launch(void* const* d_in, const int* in_sizes, int n_in,
                              void* d_out, int out_size, void* d_ws, size_t ws_size,
                              hipStream_t stream)
{
    const float* h   = (const float*)d_in[0];
    const int* src   = (const int*)d_in[1];
    const int* dst   = (const int*)d_in[2];
    const int* r     = (const int*)d_in[3];
    const int* inv   = (const int*)d_in[4];
    const float* iW1 = (const float*)d_in[5];
    const float* ib1 = (const float*)d_in[6];
    const float* iW2 = (const float*)d_in[7];
    const float* ib2 = (const float*)d_in[8];
    const float* iW3 = (const float*)d_in[9];
    const float* ib3 = (const float*)d_in[10];
    const float* aW1 = (const float*)d_in[11];
    const float* ab1 = (const float*)d_in[12];
    const float* aW2 = (const float*)d_in[13];
    const float* ab2 = (const float*)d_in[14];
    const float* aW3 = (const float*)d_in[15];
    const float* ab3 = (const float*)d_in[16];
    const float* pW1 = (const float*)d_in[17];
    const float* pb1 = (const float*)d_in[18];
    const float* pW2 = (const float*)d_in[19];
    const float* pb2 = (const float*)d_in[20];

    const int N = in_sizes[0] / 256;
    const int E = in_sizes[1];
    float* out = (float*)d_out;

    // workspace carve-up
    f16_t* zbuf = (f16_t*)d_ws;                        // 2N*128 f16 (z|zinv per node)
    int* cnt    = (int*)(zbuf + (size_t)2 * N * 128);  // N
    int* offs   = cnt + N;                             // N
    int* cursor = offs + N;                            // N
    int* bsum   = cursor + N;                          // 256
    int* ridx   = bsum + 256;                          // E
    f16_t* wp   = (f16_t*)(ridx + E);                  // WP_TOTAL packed f16
    float* c3f  = (float*)(wp + WP_TOTAL);             // 128

    (void)hipMemsetAsync(cnt, 0, (size_t)N * sizeof(int), stream);

    // 0) weight packing + folded M3/c3 (one kernel)
    pack_mc3<<<dim3(256, 9), 256, 0, stream>>>(iW1, iW2, iW3, aW1, aW2, aW3,
                                               pW1, pW2, ib3, wp, c3f);

    const int tiles = (N + 63) / 64;
    const int EB = (E + 511) / 512;
    const int NB = (N + 255) / 256;

    // 1) per-node z / zinv (f16) + fused CSR edge count
    kernelA<<<tiles + EB, 512, 0, stream>>>(h, zbuf, wp, ib1, ib2, c3f, N,
                                            tiles, dst, cnt, E);

    // 2) CSR scan + fill (ridx = src*2 + r)
    scan1<<<NB, 256, 0, stream>>>(cnt, offs, bsum, N);
    if (NB <= 256) {
        scan3b<<<NB, 256, 0, stream>>>(offs, bsum, cursor, N, NB);
    } else {
        scan2<<<1, 1, 0, stream>>>(bsum, NB);
        scan3<<<NB, 256, 0, stream>>>(offs, bsum, cursor, N);
    }
    fill_kernel<<<(E + 255) / 256, 256, 0, stream>>>(dst, src, r, cursor, ridx, E);

    // 3) fused: mean gather + L2a,L3a + cond inv-MLP + proj1,proj2
    kernelB<<<tiles, 512, 0, stream>>>(zbuf, ridx, offs, cnt, ab1, inv, out, wp,
                                       ab2, ab3, ib1, ib2, ib3, pb1, pb2, N);
}

// Round 6
// 330.167 us; speedup vs baseline: 1.2080x; 1.0275x over previous
//
#include <hip/hip_runtime.h>

typedef _Float16 f16_t;
typedef f16_t f16x2 __attribute__((ext_vector_type(2)));
typedef f16_t f16x4 __attribute__((ext_vector_type(4)));
typedef f16_t f16x8 __attribute__((ext_vector_type(8)));
typedef float f32x4 __attribute__((ext_vector_type(4)));
typedef float f32x16 __attribute__((ext_vector_type(16)));

#define MFMA16H(a, b, c) __builtin_amdgcn_mfma_f32_16x16x32_f16(a, b, c, 0, 0, 0)
#define MFMA32H(a, b, c) __builtin_amdgcn_mfma_f32_32x32x16_f16(a, b, c, 0, 0, 0)

__device__ __forceinline__ float leaky01(float v) { return v >= 0.f ? v : 0.01f * v; }

// accumulate one f16x4 row fragment into 4 f32 sums via v_dot2_f32_f16
__device__ __forceinline__ void acc_f16x4(float& s0, float& s1, float& s2, float& s3,
                                          f16x4 v)
{
#if __has_builtin(__builtin_amdgcn_fdot2)
    const f16x2 K10 = (f16x2){(f16_t)1.0f, (f16_t)0.0f};
    const f16x2 K01 = (f16x2){(f16_t)0.0f, (f16_t)1.0f};
    f16x2 lo = (f16x2){v.x, v.y};
    f16x2 hi = (f16x2){v.z, v.w};
    s0 = __builtin_amdgcn_fdot2(lo, K10, s0, false);
    s1 = __builtin_amdgcn_fdot2(lo, K01, s1, false);
    s2 = __builtin_amdgcn_fdot2(hi, K10, s2, false);
    s3 = __builtin_amdgcn_fdot2(hi, K01, s3, false);
#else
    s0 += (float)v.x; s1 += (float)v.y; s2 += (float)v.z; s3 += (float)v.w;
#endif
}

// packed-weight offsets (f16 elements)
#define OFF_IW1 0         // 256x128
#define OFF_IW2 32768     // 128x128
#define OFF_IW3 49152     // 128x256
#define OFF_AW1 81920     // 256x128
#define OFF_AW2 114688    // 128x128
#define OFF_AW3 131072    // 128x256
#define OFF_PW1 163840    // 256x256
#define OFF_PW2 229376    // 256x256
#define OFF_M3  294912    // 128x128
#define WP_TOTAL 311296

// ---------------------------------------------------------------------------
// Narrow (128-col) GEMM, 32 rows: 8 waves x 16 cols, 2 row-tiles of 16.
// ---------------------------------------------------------------------------
template<int KD, int NC>
__device__ __forceinline__ void gemm16(
    const f16_t* __restrict__ a, int sa, const f16_t* __restrict__ B,
    int cb, int qd, int ln, f32x4 (&acc)[2])
{
    acc[0] = (f32x4){0.f, 0.f, 0.f, 0.f};
    acc[1] = acc[0];
#pragma unroll
    for (int k0 = 0; k0 < KD; k0 += 32) {
        int ka = k0 + qd * 8;
        f16x8 b = *(const f16x8*)(B + ((size_t)((k0 >> 5) * 4 + qd) * NC + cb + ln) * 8);
        f16x8 a0 = *(const f16x8*)&a[ln * sa + ka];
        f16x8 a1 = *(const f16x8*)&a[(16 + ln) * sa + ka];
        acc[0] = MFMA16H(a0, b, acc[0]);
        acc[1] = MFMA16H(a1, b, acc[1]);
    }
}

// ---------------------------------------------------------------------------
// Wide GEMM, 32 rows: per wave 32 cols x one 32-row subtile.
// ---------------------------------------------------------------------------
template<int KD, int NC>
__device__ __forceinline__ void gemm32(
    const f16_t* __restrict__ a, int sa, const f16_t* __restrict__ B,
    int cb, int l31, int kh, f32x16 &o)
{
    f32x16 c;
#pragma unroll
    for (int i = 0; i < 16; ++i) c[i] = 0.f;
    const int ar = l31 * sa + kh * 8;
    const int bcol = cb + l31;
#pragma unroll
    for (int kc = 0; kc < KD; kc += 32) {
        f16x8 b0 = *(const f16x8*)(B + ((size_t)((kc >> 3) + kh) * NC + bcol) * 8);
        f16x8 b1 = *(const f16x8*)(B + ((size_t)((kc >> 3) + 2 + kh) * NC + bcol) * 8);
        f16x8 a0 = *(const f16x8*)&a[ar + kc];
        f16x8 a1 = *(const f16x8*)&a[ar + kc + 16];
        c = MFMA32H(a0, b0, c);
        c = MFMA32H(a1, b1, c);
    }
    o = c;
}

// narrow epilogue -> f16 LDS. act: 0 none, 1 leaky, 2 relu
template<int ACT>
__device__ __forceinline__ void epi16(
    f32x4 (&acc)[2], const float* __restrict__ bias,
    int cb, int qd, int ln, f16_t* d, int stride)
{
    int col = cb + ln;
    float bb = bias[col];
#pragma unroll
    for (int rt = 0; rt < 2; ++rt)
#pragma unroll
        for (int r = 0; r < 4; ++r) {
            float v = acc[rt][r] + bb;
            if (ACT == 1) v = leaky01(v);
            else if (ACT == 2) v = fmaxf(v, 0.f);
            d[(rt * 16 + qd * 4 + r) * stride + col] = (f16_t)v;
        }
}

// wide epilogue -> f16 LDS. C/D layout: col=lane&31, row=(r&3)+8*(r>>2)+4*kh.
template<int ACT>
__device__ __forceinline__ void epi32(
    const f32x16 &a0, const float* __restrict__ bias,
    int cb, int l31, int kh, f16_t* d, int stride)
{
    int col = cb + l31;
    float bb = bias[col];
#pragma unroll
    for (int r = 0; r < 16; ++r) {
        float v = a0[r] + bb;
        if (ACT == 1) v = leaky01(v);
        else if (ACT == 2) v = fmaxf(v, 0.f);
        int row = (r & 3) + 8 * (r >> 2) + 4 * kh;
        d[row * stride + col] = (f16_t)v;
    }
}

// ---------------------------------------------------------------------------
// count_kernel: CSR edge count (split from kernelA for profiler visibility)
// ---------------------------------------------------------------------------
__global__ void count_kernel(const int* __restrict__ dstE, int* __restrict__ cnt,
                             int E)
{
    int e = blockIdx.x * blockDim.x + threadIdx.x;
    if (e < E) atomicAdd(&cnt[dstE[e]], 1);
}

// ---------------------------------------------------------------------------
// kernelA: 512 thr / 32 rows, 25.6 KB LDS -> 4 blocks/CU (32 waves).
// Dual wide: waves 0-3 z = h@aW1, waves 4-7 y1 = leaky(h@iW1+ib1).
// Then y2 = leaky(y1@iW2+ib2); zinv = y2@M3 + c3.
// z staged into dead upper half of X, zinv into dead Y; coalesced store.
// ---------------------------------------------------------------------------
__global__ __launch_bounds__(512, 8) void kernelA(
    const float* __restrict__ h, f16_t* __restrict__ zbuf,
    const f16_t* __restrict__ wp, const float* __restrict__ ib1,
    const float* __restrict__ ib2, const float* __restrict__ c3f, int M)
{
    __shared__ f16_t X[32][264];
    __shared__ f16_t Y[32][136];

    const int tid = threadIdx.x;
    const int row0 = blockIdx.x * 32;
    const int lane = tid & 63;
    const int wv = tid >> 6;          // 0..7
    const int qd = lane >> 4;
    const int ln = lane & 15;
    const int cb = wv * 16;
    const int l31 = lane & 31;
    const int kh = lane >> 5;

    // stage h (32 x 256 fp32) -> f16
    {
        const float4* src4 = (const float4*)(h + (size_t)row0 * 256);
#pragma unroll
        for (int i = 0; i < 4; ++i) {
            int q = i * 512 + tid;
            int row = q >> 6;
            int kc = (q & 63) * 4;
            float4 v = make_float4(0.f, 0.f, 0.f, 0.f);
            if (row0 + row < M) v = src4[q];
            *(f16x4*)&X[row][kc] = (f16x4){(f16_t)v.x, (f16_t)v.y, (f16_t)v.z, (f16_t)v.w};
        }
    }
    __syncthreads();

    // dual wide: waves 0-3 -> z (aW1), waves 4-7 -> y1 (iW1); 32 cols/wave
    {
        const bool isz = wv < 4;
        const int cb32 = (wv & 3) * 32;
        const f16_t* Bw = wp + (isz ? OFF_AW1 : OFF_IW1);
        f32x16 z;
        gemm32<256, 128>(&X[0][0], 264, Bw, cb32, l31, kh, z);
        __syncthreads();   // all waves done reading h
        int col = cb32 + l31;
        if (isz) {
            // z -> X[:, 128+col] (staged for the coalesced store)
#pragma unroll
            for (int r = 0; r < 16; ++r) {
                int lrow = (r & 3) + 8 * (r >> 2) + 4 * kh;
                X[lrow][128 + col] = (f16_t)z[r];
            }
        } else {
            float bb = ib1[col];
#pragma unroll
            for (int r = 0; r < 16; ++r) {
                int lrow = (r & 3) + 8 * (r >> 2) + 4 * kh;
                Y[lrow][col] = (f16_t)leaky01(z[r] + bb);
            }
        }
    }
    __syncthreads();

    f32x4 a4[2];

    // y2 = leaky(y1@iW2 + ib2) -> X cols 0..127 (h dead; z at 128..255)
    gemm16<128, 128>(&Y[0][0], 136, wp + OFF_IW2, cb, qd, ln, a4);
    epi16<1>(a4, ib2, cb, qd, ln, &X[0][0], 264);
    __syncthreads();

    // zinv = y2 @ M3 + c3 -> Y (y1 dead)
    gemm16<128, 128>(&X[0][0], 264, wp + OFF_M3, cb, qd, ln, a4);
    {
        int col = cb + ln;
        float bb = c3f[col];
#pragma unroll
        for (int rt = 0; rt < 2; ++rt)
#pragma unroll
            for (int r = 0; r < 4; ++r)
                Y[rt * 16 + qd * 4 + r][col] = (f16_t)(a4[rt][r] + bb);
    }
    __syncthreads();

    // coalesced store: per node 512B contiguous = [z | zinv]
#pragma unroll
    for (int i = 0; i < 2; ++i) {
        int q = i * 512 + tid;
        int node = q >> 5;
        int seg = q & 31;
        int row = row0 + node;
        if (row < M) {
            f16x8 v = (seg < 16) ? *(const f16x8*)&X[node][128 + seg * 8]
                                 : *(const f16x8*)&Y[node][(seg - 16) * 8];
            *(f16x8*)&zbuf[(size_t)row * 256 + seg * 8] = v;
        }
    }
}

// ---------------------------------------------------------------------------
// kernelB: 512 thr / 32 rows, 25.9 KB LDS -> 4 blocks/CU (32 waves).
// Phase 0 = mean gather (half-wave per node, 2 passes).
// ---------------------------------------------------------------------------
__global__ __launch_bounds__(512, 8) void kernelB(
    const f16_t* __restrict__ zbuf, const int* __restrict__ ridx,
    const int* __restrict__ offs, const int* __restrict__ cnt,
    const float* __restrict__ ab1, const int* __restrict__ invf,
    float* __restrict__ out, const f16_t* __restrict__ wp,
    const float* __restrict__ ab2, const float* __restrict__ ab3,
    const float* __restrict__ ib1, const float* __restrict__ ib2,
    const float* __restrict__ ib3, const float* __restrict__ pb1,
    const float* __restrict__ pb2, int M)
{
    __shared__ f16_t C[32][264];
    __shared__ f16_t A[32][136];
    __shared__ int sflag[32];

    const int tid = threadIdx.x;
    const int row0 = blockIdx.x * 32;
    const int lane = tid & 63;
    const int wv = tid >> 6;
    const int qd = lane >> 4;
    const int ln = lane & 15;
    const int cb2 = wv * 16;
    const int l31 = lane & 31;
    const int kh = lane >> 5;
    const int cb32 = wv * 32;

    // ---- phase 0: mean gather, half-wave (32 lanes x f16x4 = 256B row) per node
    const int hw = tid >> 5;          // half-wave 0..15
    const int hl = tid & 31;          // lane in half
    const int hbase = lane & 32;      // shfl base within wave
    const f16x4* zp4 = (const f16x4*)zbuf;   // row = 32 f16x4

#pragma unroll
    for (int pass = 0; pass < 2; ++pass) {
        int nl = pass * 16 + hw;
        int row = row0 + nl;
        float s0 = 0.f, s1 = 0.f, s2 = 0.f, s3 = 0.f;
        int c = 0;
        if (row < M) {
            int beg = offs[row];
            c = cnt[row];
            for (int base = 0; base < c; base += 32) {
                int rem = c - base; if (rem > 32) rem = 32;
                int myr = (hl < rem) ? ridx[beg + base + hl] : 0;
                int j = 0;
                for (; j + 16 <= rem; j += 16) {
                    f16x4 v[16];
#pragma unroll
                    for (int i = 0; i < 16; ++i) {
                        int rr = __shfl(myr, hbase + j + i);
                        v[i] = zp4[(size_t)rr * 32 + hl];
                    }
#pragma unroll
                    for (int i = 0; i < 16; ++i)
                        acc_f16x4(s0, s1, s2, s3, v[i]);
                }
                for (; j + 8 <= rem; j += 8) {
                    f16x4 v[8];
#pragma unroll
                    for (int i = 0; i < 8; ++i) {
                        int rr = __shfl(myr, hbase + j + i);
                        v[i] = zp4[(size_t)rr * 32 + hl];
                    }
#pragma unroll
                    for (int i = 0; i < 8; ++i)
                        acc_f16x4(s0, s1, s2, s3, v[i]);
                }
                for (; j < rem; ++j) {
                    int rr = __shfl(myr, hbase + j);
                    f16x4 vv = zp4[(size_t)rr * 32 + hl];
                    acc_f16x4(s0, s1, s2, s3, vv);
                }
            }
        }
        float invc = 1.0f / fmaxf((float)c, 1.0f);
        float4 bv = *(const float4*)&ab1[hl * 4];
        float m0 = leaky01(s0 * invc + bv.x);
        float m1 = leaky01(s1 * invc + bv.y);
        float m2 = leaky01(s2 * invc + bv.z);
        float m3 = leaky01(s3 * invc + bv.w);
        *(f16x4*)&A[nl][hl * 4] = (f16x4){(f16_t)m0, (f16_t)m1, (f16_t)m2, (f16_t)m3};
    }
    if (tid < 32) {
        int rr = row0 + tid;
        sflag[tid] = (rr < M) ? invf[rr] : 0;
    }
    __syncthreads();

    f32x4 a4[2];
    f32x16 c32;

    // L2a: u = leaky(y@aW2 + ab2) -> A (in place)
    gemm16<128, 128>(&A[0][0], 136, wp + OFF_AW2, cb2, qd, ln, a4);
    __syncthreads();
    epi16<1>(a4, ab2, cb2, qd, ln, &A[0][0], 136);
    __syncthreads();

    // L3a: res = u@aW3 + ab3 -> C
    gemm32<128, 256>(&A[0][0], 136, wp + OFF_AW3, cb32, l31, kh, c32);
    epi32<0>(c32, ab3, cb32, l31, kh, &C[0][0], 264);
    __syncthreads();

    // inv layer1: t1 = leaky(res@iW1 + ib1) -> A
    gemm16<256, 128>(&C[0][0], 264, wp + OFF_IW1, cb2, qd, ln, a4);
    epi16<1>(a4, ib1, cb2, qd, ln, &A[0][0], 136);
    __syncthreads();

    // inv layer2: t2 = leaky(t1@iW2 + ib2) -> A (in place)
    gemm16<128, 128>(&A[0][0], 136, wp + OFF_IW2, cb2, qd, ln, a4);
    __syncthreads();
    epi16<1>(a4, ib2, cb2, qd, ln, &A[0][0], 136);
    __syncthreads();

    // inv layer3: overwrite C rows where flag set
    gemm32<128, 256>(&A[0][0], 136, wp + OFF_IW3, cb32, l31, kh, c32);
    {
        int col = cb32 + l31;
        float bb = ib3[col];
#pragma unroll
        for (int r = 0; r < 16; ++r) {
            int lrow = (r & 3) + 8 * (r >> 2) + 4 * kh;
            if (sflag[lrow] == 1) C[lrow][col] = (f16_t)(c32[r] + bb);
        }
    }
    __syncthreads();

    // proj1: p1 = relu(sel@pW1 + pb1) -> C (in place)
    gemm32<256, 256>(&C[0][0], 264, wp + OFF_PW1, cb32, l31, kh, c32);
    __syncthreads();
    epi32<2>(c32, pb1, cb32, l31, kh, &C[0][0], 264);
    __syncthreads();

    // proj2 -> out
    gemm32<256, 256>(&C[0][0], 264, wp + OFF_PW2, cb32, l31, kh, c32);
    {
        int col = cb32 + l31;
        float bb = pb2[col];
#pragma unroll
        for (int r = 0; r < 16; ++r) {
            int lrow = (r & 3) + 8 * (r >> 2) + 4 * kh;
            int row = row0 + lrow;
            if (row < M) out[(size_t)row * 256 + col] = c32[r] + bb;
        }
    }
}

// ---------------------------------------------------------------------------
// pack_mc3: fp32 W[K][Nc] -> f16 in B-fragment order [k>>3][n][k&7].
// m==8 blocks compute M3 = iW3@aW1 on the fly; block 64 computes c3.
// ---------------------------------------------------------------------------
__global__ void pack_mc3(const float* s0, const float* s1, const float* s2,
                         const float* s3, const float* s4, const float* s5,
                         const float* s6, const float* s7,
                         const float* __restrict__ ib3, f16_t* dst,
                         float* __restrict__ c3f)
{
    int m = blockIdx.y;
    int bx = blockIdx.x;
    if (m == 8) {
        if (bx < 64) {
            int idx = bx * 256 + threadIdx.x;      // < 16384
            int k = idx >> 7, j = idx & 127;
            float s = 0.f;
            for (int t = 0; t < 256; ++t) s += s2[k * 256 + t] * s3[t * 128 + j];
            int p = ((k >> 3) * 128 + j) * 8 + (k & 7);
            dst[OFF_M3 + p] = (f16_t)s;
        } else if (bx == 64) {
            int j = threadIdx.x;
            if (j < 128) {
                float s = 0.f;
                for (int t = 0; t < 256; ++t) s += ib3[t] * s3[t * 128 + j];
                c3f[j] = s;
            }
        }
        return;
    }
    const float* srcs[8] = {s0, s1, s2, s3, s4, s5, s6, s7};
    const int lgN[8] = {7, 7, 8, 7, 7, 8, 8, 8};
    const int sz[8]  = {32768, 16384, 32768, 32768, 16384, 32768, 65536, 65536};
    const int off[8] = {OFF_IW1, OFF_IW2, OFF_IW3, OFF_AW1, OFF_AW2, OFF_AW3,
                        OFF_PW1, OFF_PW2};
    int idx = bx * blockDim.x + threadIdx.x;
    if (idx >= sz[m]) return;
    int lg = lgN[m];
    int Nc = 1 << lg;
    int k = idx >> lg;
    int n = idx & (Nc - 1);
    int p = ((k >> 3) * Nc + n) * 8 + (k & 7);
    dst[off[m] + p] = (f16_t)srcs[m][idx];
}

// ---------------------------------------------------------------------------
// CSR build: scan1 -> scan3b (merged scan2) -> fill
// ---------------------------------------------------------------------------
__global__ void scan1(const int* __restrict__ cnt, int* __restrict__ offs,
                      int* __restrict__ bsum, int Nn)
{
    __shared__ int s[256];
    int tid = threadIdx.x;
    int g = blockIdx.x * 256 + tid;
    int v = (g < Nn) ? cnt[g] : 0;
    s[tid] = v;
    __syncthreads();
    for (int off = 1; off < 256; off <<= 1) {
        int u = (tid >= off) ? s[tid - off] : 0;
        __syncthreads();
        s[tid] += u;
        __syncthreads();
    }
    if (g < Nn) offs[g] = s[tid] - v;          // block-exclusive
    if (tid == 255) bsum[blockIdx.x] = s[255];
}

// requires NB <= 256 (true at N=50k: NB=196)
__global__ void scan3b(int* __restrict__ offs, const int* __restrict__ bsum,
                       int* __restrict__ cursor, int Nn, int NB)
{
    __shared__ int s[256];
    int tid = threadIdx.x;
    int bid = blockIdx.x;
    int v = (tid < NB) ? bsum[tid] : 0;
    s[tid] = v;
    __syncthreads();
    for (int off = 1; off < 256; off <<= 1) {
        int u = (tid >= off) ? s[tid - off] : 0;
        __syncthreads();
        s[tid] += u;
        __syncthreads();
    }
    int base = (bid > 0) ? s[bid - 1] : 0;     // sum of bsum[0..bid-1]
    int g = bid * 256 + tid;
    if (g < Nn) {
        int o = offs[g] + base;
        offs[g] = o;
        cursor[g] = o;
    }
}

// fallback path kernels (NB > 256; unused at N=50k)
__global__ void scan2(int* __restrict__ bsum, int NB)
{
    if (threadIdx.x == 0) {
        int run = 0;
        for (int i = 0; i < NB; ++i) { int v = bsum[i]; bsum[i] = run; run += v; }
    }
}

__global__ void scan3(int* __restrict__ offs, const int* __restrict__ bsum,
                      int* __restrict__ cursor, int Nn)
{
    int g = blockIdx.x * 256 + threadIdx.x;
    if (g < Nn) {
        int o = offs[g] + bsum[blockIdx.x];
        offs[g] = o;
        cursor[g] = o;
    }
}

__global__ void fill_kernel(const int* __restrict__ dst, const int* __restrict__ src,
                            const int* __restrict__ r, int* __restrict__ cursor,
                            int* __restrict__ ridx, int E)
{
    int e = blockIdx.x * blockDim.x + threadIdx.x;
    if (e < E) {
        int p = atomicAdd(&cursor[dst[e]], 1);
        ridx[p] = src[e] * 2 + r[e];
    }
}

extern "C" void kernel_launch(void* const* d_in, const int* in_sizes, int n_in,
                              void* d_out, int out_size, void* d_ws, size_t ws_size,
                              hipStream_t stream)
{
    const float* h   = (const float*)d_in[0];
    const int* src   = (const int*)d_in[1];
    const int* dst   = (const int*)d_in[2];
    const int* r     = (const int*)d_in[3];
    const int* inv   = (const int*)d_in[4];
    const float* iW1 = (const float*)d_in[5];
    const float* ib1 = (const float*)d_in[6];
    const float* iW2 = (const float*)d_in[7];
    const float* ib2 = (const float*)d_in[8];
    const float* iW3 = (const float*)d_in[9];
    const float* ib3 = (const float*)d_in[10];
    const float* aW1 = (const float*)d_in[11];
    const float* ab1 = (const float*)d_in[12];
    const float* aW2 = (const float*)d_in[13];
    const float* ab2 = (const float*)d_in[14];
    const float* aW3 = (const float*)d_in[15];
    const float* ab3 = (const float*)d_in[16];
    const float* pW1 = (const float*)d_in[17];
    const float* pb1 = (const float*)d_in[18];
    const float* pW2 = (const float*)d_in[19];
    const float* pb2 = (const float*)d_in[20];

    const int N = in_sizes[0] / 256;
    const int E = in_sizes[1];
    float* out = (float*)d_out;

    // workspace carve-up
    f16_t* zbuf = (f16_t*)d_ws;                        // 2N*128 f16 (z|zinv per node)
    int* cnt    = (int*)(zbuf + (size_t)2 * N * 128);  // N
    int* offs   = cnt + N;                             // N
    int* cursor = offs + N;                            // N
    int* bsum   = cursor + N;                          // 256
    int* ridx   = bsum + 256;                          // E
    f16_t* wp   = (f16_t*)(ridx + E);                  // WP_TOTAL packed f16
    float* c3f  = (float*)(wp + WP_TOTAL);             // 128

    (void)hipMemsetAsync(cnt, 0, (size_t)N * sizeof(int), stream);

    // 0) weight packing + folded M3/c3
    pack_mc3<<<dim3(256, 9), 256, 0, stream>>>(iW1, iW2, iW3, aW1, aW2, aW3,
                                               pW1, pW2, ib3, wp, c3f);

    const int tiles = (N + 31) / 32;
    const int EB = (E + 511) / 512;
    const int NB = (N + 255) / 256;

    // 1) CSR edge count (own dispatch for profiler attribution)
    count_kernel<<<EB, 512, 0, stream>>>(dst, cnt, E);

    // 2) per-node z / zinv (f16)
    kernelA<<<tiles, 512, 0, stream>>>(h, zbuf, wp, ib1, ib2, c3f, N);

    // 3) CSR scan + fill (ridx = src*2 + r)
    scan1<<<NB, 256, 0, stream>>>(cnt, offs, bsum, N);
    if (NB <= 256) {
        scan3b<<<NB, 256, 0, stream>>>(offs, bsum, cursor, N, NB);
    } else {
        scan2<<<1, 1, 0, stream>>>(bsum, NB);
        scan3<<<NB, 256, 0, stream>>>(offs, bsum, cursor, N);
    }
    fill_kernel<<<(E + 255) / 256, 256, 0, stream>>>(dst, src, r, cursor, ridx, E);

    // 4) fused: mean gather + L2a,L3a + cond inv-MLP + proj1,proj2
    kernelB<<<tiles, 512, 0, stream>>>(zbuf, ridx, offs, cnt, ab1, inv, out, wp,
                                       ab2, ab3, ib1, ib2, ib3, pb1, pb2, N);
}